// Round 18
// baseline (278.427 us; speedup 1.0000x reference)
//
#include <hip/hip_runtime.h>
#include <stdint.h>

#define BATCH 4
#define CH    256
#define NTOK  4096
#define KSEL  409          // int(0.1 * 4096)

typedef unsigned short u16;
typedef unsigned int   u32;
typedef unsigned long long u64;

typedef __attribute__((ext_vector_type(8))) _Float16 half8;
typedef __attribute__((ext_vector_type(4))) _Float16 half4;
typedef __attribute__((ext_vector_type(4))) float f32x4;
typedef __attribute__((ext_vector_type(4))) u32 u32x4;
typedef __attribute__((ext_vector_type(2))) u32 u32x2;
typedef __attribute__((ext_vector_type(4))) float fl4;

// ---------------- helpers ----------------
__device__ inline u16 h2u(_Float16 h){ u16 u; __builtin_memcpy(&u,&h,2); return u; }
__device__ inline float u2f16(u32 v){ _Float16 h; u16 uu=(u16)v; __builtin_memcpy(&h,&uu,2); return (float)h; }
// monotone 16-bit fp16<->uint key transform (ascending)
__device__ inline float kinv16(u32 k){
  u32 v = (k & 0x8000u) ? (k & 0x7FFFu) : ((~k) & 0xFFFFu);
  return u2f16(v);
}
__device__ inline u32 ktf16(u32 a){
  return (a & 0x8000u) ? ((~a) & 0xFFFFu) : (a | 0x8000u);
}
__device__ inline void gload16(const void* g, void* l){
  __builtin_amdgcn_global_load_lds((const __attribute__((address_space(1))) u32*)g,
                                   (__attribute__((address_space(3))) u32*)l, 16, 0, 0);
}
// scan a 256-bin per-wave histogram: returns enc = digit<<22 | binCount<<9 | remK
__device__ inline u32 hist_scan(const u32* histw, int lane, u32 kr){
  u32x4 h = *(const u32x4*)&histw[lane<<2];
  u32 tot = h[0]+h[1]+h[2]+h[3];
  u32 sfx = tot;
  #pragma unroll
  for (int off=1; off<64; off<<=1) {
    u32 v = __shfl_down(sfx, off, 64);
    if (lane + off < 64) sfx += v;
  }
  u32 s3 = (sfx - tot) + h[3];
  u32 s2 = s3 + h[2];
  u32 s1 = s2 + h[1];
  u32 s0 = s1 + h[0];
  u32 s4 = s3 - h[3];
  u32 enc = 0;
  if (s0 >= kr && s1 < kr) enc = ((u32)((lane<<2)+0)<<22) | (h[0]<<9) | (kr - s1);
  if (s1 >= kr && s2 < kr) enc = ((u32)((lane<<2)+1)<<22) | (h[1]<<9) | (kr - s2);
  if (s2 >= kr && s3 < kr) enc = ((u32)((lane<<2)+2)<<22) | (h[2]<<9) | (kr - s3);
  if (s3 >= kr && s4 < kr) enc = ((u32)((lane<<2)+3)<<22) | (h[3]<<9) | (kr - s4);
  #pragma unroll
  for (int off=32; off; off>>=1) { u32 o = __shfl_xor(enc, off, 64); enc = (o>enc)? o:enc; }
  return enc;
}

// ---------------- phase -1: W split ----------------
__global__ __launch_bounds__(256) void wsplit_kernel(
    const float* __restrict__ Wq, const float* __restrict__ Wk,
    const float* __restrict__ Wv, u16* __restrict__ W3h, u16* __restrict__ W3l)
{
  const int p = blockIdx.y;
  const float* W = (p==0)? Wq : (p==1)? Wk : Wv;
  const int idx = (blockIdx.x*256 + threadIdx.x) * 4;
  fl4 v = *(const fl4*)(W + idx);
  u32x2 vh, vl;
  #pragma unroll
  for (int q=0;q<2;q++) {
    _Float16 h0=(_Float16)v[q*2], h1=(_Float16)v[q*2+1];
    _Float16 l0=(_Float16)(v[q*2]-(float)h0), l1=(_Float16)(v[q*2+1]-(float)h1);
    vh[q] = (u32)h2u(h0) | ((u32)h2u(h1)<<16);
    vl[q] = (u32)h2u(l0) | ((u32)h2u(l1)<<16);
  }
  *(u32x2*)(W3h + p*CH*CH + idx) = vh;
  *(u32x2*)(W3l + p*CH*CH + idx) = vl;
}

// ---------------- phase 0a: x transpose + split ----------------
__global__ __launch_bounds__(256) void xsplit_kernel(
    const float* __restrict__ x, u16* __restrict__ xTh, u16* __restrict__ xTl)
{
  __shared__ float lds[64][65];
  const int tid = threadIdx.x;
  const int n0 = blockIdx.x << 6;
  const int c0 = blockIdx.y << 6;
  const int b  = blockIdx.z;
  const float* xb = x + (size_t)b*CH*NTOK;

  #pragma unroll
  for (int i=0;i<16;i++) {
    int c_l = (tid>>6) + (i<<2);
    int n_l = tid & 63;
    lds[c_l][n_l] = xb[(size_t)(c0+c_l)*NTOK + n0 + n_l];
  }
  __syncthreads();
  u16* oh = xTh + (size_t)b*NTOK*CH;
  u16* ol = xTl + (size_t)b*NTOK*CH;
  #pragma unroll
  for (int i=0;i<16;i++) {
    int n_l = (tid>>6) + (i<<2);
    int c_l = tid & 63;
    float v = lds[c_l][n_l];
    _Float16 h = (_Float16)v;
    _Float16 l = (_Float16)(v - (float)h);
    size_t o = (size_t)(n0+n_l)*CH + c0 + c_l;
    oh[o] = h2u(h);
    ol[o] = h2u(l);
  }
}

// ---------------- phase 0b: QKV projection GEMM ----------------
__global__ __launch_bounds__(256) void proj_gemm(
    const u16* __restrict__ xTh, const u16* __restrict__ xTl,
    const u16* __restrict__ W3h, const u16* __restrict__ W3l,
    u16* __restrict__ Qh, u16* __restrict__ Kh, u16* __restrict__ Vc)
{
  __shared__ __align__(16) short lds[4*128*64];   // ah, al, bh, bl (16KB each)
  short* lds_ah = lds;
  short* lds_al = lds + 128*64;
  short* lds_bh = lds + 2*128*64;
  short* lds_bl = lds + 3*128*64;

  const int tid  = threadIdx.x;
  const int lane = tid & 63;
  const int wave = tid >> 6;
  const int wm = wave >> 1, wn = wave & 1;
  const int brow = blockIdx.x << 7;     // token tile
  const int bcol = blockIdx.y << 7;     // out-channel tile
  const int z = blockIdx.z;             // b*3 + p
  const int b = z / 3, p = z - 3*b;

  const u16* Agh = xTh + ((size_t)b*NTOK + brow)*CH;
  const u16* Agl = xTl + ((size_t)b*NTOK + brow)*CH;
  const u16* Bgh = W3h + (size_t)p*CH*CH + (size_t)bcol*CH;
  const u16* Bgl = W3l + (size_t)p*CH*CH + (size_t)bcol*CH;

  f32x4 acc[4][4];
  #pragma unroll
  for (int i=0;i<4;i++)
    #pragma unroll
    for (int j=0;j<4;j++) acc[i][j] = (f32x4)0.f;

  const int sr    = tid >> 3;
  const int sslot = tid & 7;

  for (int kt=0; kt<4; kt++) {
    #pragma unroll
    for (int c=0;c<4;c++) {
      int r  = (c<<5) + sr;
      int ss = sslot ^ (r & 7);
      size_t goff = (size_t)r*CH + (kt<<6) + (ss<<3);
      int dst = (c<<12) + (wave<<10);
      gload16(Agh + goff, (char*)lds_ah + dst);
      gload16(Agl + goff, (char*)lds_al + dst);
      gload16(Bgh + goff, (char*)lds_bh + dst);
      gload16(Bgl + goff, (char*)lds_bl + dst);
    }
    __syncthreads();
    #pragma unroll
    for (int ks=0;ks<2;ks++) {
      half8 ah[4], al[4], bh[4], bl[4];
      const int kg = lane >> 4;
      const int rl = lane & 15;
      #pragma unroll
      for (int t=0;t<4;t++) {
        int ar = (wm<<6) + (t<<4) + rl;
        int slot = (ks<<2) + kg;
        int ao = ar*64 + ((slot ^ (ar&7))<<3);
        ah[t] = *(const half8*)&lds_ah[ao];
        al[t] = *(const half8*)&lds_al[ao];
        int br = (wn<<6) + (t<<4) + rl;
        int bo = br*64 + ((slot ^ (br&7))<<3);
        bh[t] = *(const half8*)&lds_bh[bo];
        bl[t] = *(const half8*)&lds_bl[bo];
      }
      #pragma unroll
      for (int mt=0;mt<4;mt++)
        #pragma unroll
        for (int nt=0;nt<4;nt++) {
          acc[mt][nt] = __builtin_amdgcn_mfma_f32_16x16x32_f16(ah[mt], bh[nt], acc[mt][nt], 0,0,0);
          acc[mt][nt] = __builtin_amdgcn_mfma_f32_16x16x32_f16(ah[mt], bl[nt], acc[mt][nt], 0,0,0);
          acc[mt][nt] = __builtin_amdgcn_mfma_f32_16x16x32_f16(al[mt], bh[nt], acc[mt][nt], 0,0,0);
        }
    }
    __syncthreads();
  }

  const int rl = lane & 15, rg = lane >> 4;
  if (p < 2) {
    u16* oh = ((p==0)? Qh : Kh) + (size_t)b*NTOK*CH;
    #pragma unroll
    for (int mt=0;mt<4;mt++) {
      #pragma unroll
      for (int nt=0;nt<4;nt++) {
        int n = brow + (wm<<6) + (mt<<4) + (rg<<2);
        int c = bcol + (wn<<6) + (nt<<4) + rl;
        #pragma unroll
        for (int r=0;r<4;r++)
          oh[(size_t)(n+r)*CH + c] = h2u((_Float16)acc[mt][nt][r]);
      }
    }
  } else {
    // V: transpose in LDS -> store channel-major Vc[b][d][n] coalesced
    u16* ldsT = (u16*)lds;                 // [128][136] u16
    #pragma unroll
    for (int mt=0;mt<4;mt++) {
      #pragma unroll
      for (int nt=0;nt<4;nt++) {
        int n_l = (wm<<6) + (mt<<4) + (rg<<2);
        int c_l = (wn<<6) + (nt<<4) + rl;
        half4 hv;
        #pragma unroll
        for (int r=0;r<4;r++) hv[r] = (_Float16)acc[mt][nt][r];
        *(half4*)&ldsT[c_l*136 + n_l] = hv;
      }
    }
    __syncthreads();
    u16* ov = Vc + (size_t)b*CH*NTOK + (size_t)bcol*NTOK + brow;
    #pragma unroll
    for (int i=0;i<32;i++) {
      int d_l = (tid>>6) + (i<<2);
      u32 v = *(const u32*)&ldsT[d_l*136 + (lane<<1)];
      *(u32*)(ov + (size_t)d_l*NTOK + (lane<<1)) = v;
    }
  }
}

// ============ counted-vmcnt pipeline macros (T4: never drain vmcnt to 0 mid-loop) ============
#define WAITV(S)  asm volatile("s_waitcnt " S ::: "memory")
#define RBAR()    __builtin_amdgcn_s_barrier()
#define SCHED0()  __builtin_amdgcn_sched_barrier(0)

// ---------------- phase 1: S = Q*K^T / 16, hi-only fp16, fp16 out, 2-deep pipeline ----------------
#define STAGE_SC(LA, LB, KT)                                                  \
  {                                                                           \
    _Pragma("unroll")                                                         \
    for (int c=0;c<4;c++) {                                                   \
      int r  = (c<<5) + sr;                                                   \
      int ss = sslot ^ (r & 7);                                               \
      size_t goff = (size_t)r*CH + ((KT)<<6) + (ss<<3);                       \
      gload16(Ag + goff, (char*)(LA) + (c<<12) + (wave<<10));                 \
      gload16(Bg + goff, (char*)(LB) + (c<<12) + (wave<<10));                 \
    }                                                                         \
  }

#define COMP_SC(LA, LB)                                                       \
  {                                                                           \
    _Pragma("unroll")                                                         \
    for (int ks=0;ks<2;ks++) {                                                \
      half8 af[4], bf[4];                                                     \
      const int kg = lane >> 4;                                               \
      const int rl = lane & 15;                                               \
      _Pragma("unroll")                                                       \
      for (int t=0;t<4;t++) {                                                 \
        int ar = (wm<<6) + (t<<4) + rl;                                       \
        int slot = (ks<<2) + kg;                                              \
        af[t] = *(const half8*)&(LA)[ar*64 + ((slot ^ (ar&7))<<3)];           \
        int br = (wn<<6) + (t<<4) + rl;                                       \
        bf[t] = *(const half8*)&(LB)[br*64 + ((slot ^ (br&7))<<3)];           \
      }                                                                       \
      _Pragma("unroll")                                                       \
      for (int mt=0;mt<4;mt++)                                                \
        _Pragma("unroll")                                                     \
        for (int nt=0;nt<4;nt++)                                              \
          acc[mt][nt] = __builtin_amdgcn_mfma_f32_16x16x32_f16(af[mt], bf[nt], acc[mt][nt], 0,0,0); \
    }                                                                         \
  }

__global__ __launch_bounds__(256) void score_kernel(
    const u16* __restrict__ Qh, const u16* __restrict__ Kh,
    u16* __restrict__ S, int b_base, size_t sstride)
{
  __shared__ __align__(16) short lds_a0[128*64];
  __shared__ __align__(16) short lds_a1[128*64];
  __shared__ __align__(16) short lds_b0[128*64];
  __shared__ __align__(16) short lds_b1[128*64];
  const int tid  = threadIdx.x;
  const int lane = tid & 63;
  const int wave = tid >> 6;
  const int wm = wave >> 1, wn = wave & 1;
  const int brow = blockIdx.x << 7, bcol = blockIdx.y << 7;
  const int b = b_base + blockIdx.z;
  u16* Sb = S + (size_t)blockIdx.z * sstride;

  const u16* Ag = Qh + ((size_t)b*NTOK + brow)*CH;
  const u16* Bg = Kh + ((size_t)b*NTOK + bcol)*CH;

  f32x4 acc[4][4];
  #pragma unroll
  for (int i=0;i<4;i++)
    #pragma unroll
    for (int j=0;j<4;j++) acc[i][j] = (f32x4)0.f;

  const int sr    = tid >> 3;
  const int sslot = tid & 7;

  STAGE_SC(lds_a0, lds_b0, 0);
  STAGE_SC(lds_a1, lds_b1, 1);
  // t=0
  WAITV("vmcnt(8)"); RBAR(); SCHED0();
  COMP_SC(lds_a0, lds_b0);
  RBAR(); SCHED0();
  STAGE_SC(lds_a0, lds_b0, 2);
  // t=1
  WAITV("vmcnt(8)"); RBAR(); SCHED0();
  COMP_SC(lds_a1, lds_b1);
  RBAR(); SCHED0();
  STAGE_SC(lds_a1, lds_b1, 3);
  // t=2
  WAITV("vmcnt(8)"); RBAR(); SCHED0();
  COMP_SC(lds_a0, lds_b0);
  RBAR(); SCHED0();
  // t=3
  WAITV("vmcnt(0)"); RBAR(); SCHED0();
  COMP_SC(lds_a1, lds_b1);

  const int rl = lane & 15, rg = lane >> 4;
  #pragma unroll
  for (int mt=0;mt<4;mt++) {
    #pragma unroll
    for (int nt=0;nt<4;nt++) {
      int row = brow + (wm<<6) + (mt<<4) + (rg<<2);
      int col = bcol + (wn<<6) + (nt<<4) + rl;
      #pragma unroll
      for (int r=0;r<4;r++)
        Sb[(size_t)(row+r)*NTOK + col] = h2u((_Float16)(acc[mt][nt][r] * 0.0625f));
    }
  }
}

// ---------------- phase 2: exact per-row top-KSEL on fp16 scores, IN-PLACE S->W ----------------
// v4: STREAMING — no key[64] register array (round-14's version spilled it to scratch:
// VGPR_Count=56 < 64 keys). Each phase re-reads the row slice (8 KB/wave, L1/L2-hot).
// Semantics bit-identical to round-14: same histogram+fences, same enc encoding, same
// fast/slow tie paths (ch-order ballots), same fp op order for z and weights.
__global__ __launch_bounds__(256) void select_kernel(u16* Sh, size_t sstride)
{
  __shared__ __align__(16) u32 hist[4][256];
  const int lane = threadIdx.x & 63;
  const int wave = threadIdx.x >> 6;
  const int row  = (blockIdx.x << 2) + wave;
  u16* Srow = Sh + (size_t)blockIdx.y * sstride + (size_t)row * NTOK + (lane << 3);

  // ---- pass 0: fused load + transform + umax + high-byte histogram (streaming) ----
  #pragma unroll
  for (int i=0;i<4;i++) hist[wave][(i<<6)+lane] = 0u;
  __asm__ volatile("s_waitcnt lgkmcnt(0)" ::: "memory");
  u32 umax = 0;
  #pragma unroll
  for (int g=0; g<8; ++g) {
    u32x4 q = *(const u32x4*)(Srow + (g<<9));
    #pragma unroll
    for (int j=0; j<4; ++j) {
      u32 w = q[j];
      u32 a = ktf16(w & 0xFFFFu), bb = ktf16(w >> 16);
      umax = umax > a  ? umax : a;
      umax = umax > bb ? umax : bb;
      atomicAdd(&hist[wave][a  >> 8], 1u);
      atomicAdd(&hist[wave][bb >> 8], 1u);
    }
  }
  #pragma unroll
  for (int off=32; off; off>>=1) { u32 o = __shfl_xor(umax, off, 64); umax = o>umax ? o : umax; }
  const float m = kinv16(umax);
  __asm__ volatile("s_waitcnt lgkmcnt(0)" ::: "memory");

  u32 enc = hist_scan(hist[wave], lane, KSEL);
  u32 prefix = (enc >> 22) << 8;
  u32 krem   = enc & 0x1FFu;

  // ---- pass 1: reload + low-byte histogram within the threshold high-byte bin ----
  #pragma unroll
  for (int i=0;i<4;i++) hist[wave][(i<<6)+lane] = 0u;
  __asm__ volatile("s_waitcnt lgkmcnt(0)" ::: "memory");
  const u32 b1 = prefix >> 8;
  #pragma unroll
  for (int g=0; g<8; ++g) {
    u32x4 q = *(const u32x4*)(Srow + (g<<9));
    #pragma unroll
    for (int j=0; j<4; ++j) {
      u32 w = q[j];
      u32 a = ktf16(w & 0xFFFFu), bb = ktf16(w >> 16);
      if ((a  >> 8) == b1) atomicAdd(&hist[wave][a  & 255u], 1u);
      if ((bb >> 8) == b1) atomicAdd(&hist[wave][bb & 255u], 1u);
    }
  }
  __asm__ volatile("s_waitcnt lgkmcnt(0)" ::: "memory");
  enc = hist_scan(hist[wave], lane, krem);
  prefix |= (enc >> 22);
  const u32 cb = (enc >> 9) & 0x1FFFu;
  krem = enc & 0x1FFu;
  const u32 tkey = prefix;                    // exact KSEL-th-largest fp16 key
  const bool fast = (cb == krem);

  // ---- slow path only: ballot-ordered tie selection bitmask (ch order) ----
  u64 selb = 0;
  if (!fast) {
    const u64 ltmask = (1ull << lane) - 1ull;
    int eqbase = 0;
    #pragma unroll
    for (int g=0; g<8; ++g) {
      u32x4 q = *(const u32x4*)(Srow + (g<<9));
      #pragma unroll
      for (int j=0; j<4; ++j) {
        u32 w = q[j];
        #pragma unroll
        for (int hh=0; hh<2; ++hh) {
          u32 k = ktf16(hh ? (w >> 16) : (w & 0xFFFFu));
          int idx = (g<<3)+(j<<1)+hh;
          bool eq = (k == tkey);
          u64 eqm = __ballot(eq);
          bool sel = (k > tkey) || (eq && (eqbase + __popcll(eqm & ltmask)) < (int)krem);
          if (sel) selb |= (1ull << idx);
          eqbase += __popcll(eqm);
        }
      }
    }
  }

  // ---- z pass: reload, exp in ch order, accumulate over selected ----
  float z = 0.f;
  #pragma unroll
  for (int g=0; g<8; ++g) {
    u32x4 q = *(const u32x4*)(Srow + (g<<9));
    #pragma unroll
    for (int j=0; j<4; ++j) {
      u32 w = q[j];
      #pragma unroll
      for (int hh=0; hh<2; ++hh) {
        u32 k = ktf16(hh ? (w >> 16) : (w & 0xFFFFu));
        int idx = (g<<3)+(j<<1)+hh;
        float e = __expf(kinv16(k) - m);
        bool sel = fast ? (k >= tkey) : (((selb >> idx) & 1ull) != 0);
        if (sel) z += e;
      }
    }
  }
  #pragma unroll
  for (int off=32; off; off>>=1) z += __shfl_xor(z, off, 64);
  const float invZ = 1.f / z;

  // ---- write pass: reload, recompute exp, scale, pack, in-place coalesced store ----
  #pragma unroll
  for (int g=0; g<8; ++g) {
    u32x4 q = *(const u32x4*)(Srow + (g<<9));
    u32x4 v;
    #pragma unroll
    for (int j=0; j<4; ++j) {
      u32 w = q[j];
      u32 k0 = ktf16(w & 0xFFFFu), k1 = ktf16(w >> 16);
      int i0 = (g<<3)+(j<<1);
      bool s0 = fast ? (k0 >= tkey) : (((selb >> i0) & 1ull) != 0);
      bool s1 = fast ? (k1 >= tkey) : (((selb >> (i0+1)) & 1ull) != 0);
      float w0 = s0 ? __expf(kinv16(k0) - m) * invZ : 0.f;
      float w1 = s1 ? __expf(kinv16(k1) - m) * invZ : 0.f;
      v[j] = (u32)h2u((_Float16)w0) | ((u32)h2u((_Float16)w1) << 16);
    }
    *(u32x4*)(Srow + (g<<9)) = v;
  }
}

// ---------------- phase 3: dense PV GEMM, 2-deep counted-vmcnt pipeline ----------------
// out^T[c,n] = sum_k Vc[c,k] * Wd[n,k].  128(M=ch) x 64(N=tok) tiles, K=NTOK, BK=64.
// Wd aliases S: freshly rewritten by select -> L3-resident at launch.
#define STAGE_PV(LA, LB, KT)                                                  \
  {                                                                           \
    _Pragma("unroll")                                                         \
    for (int c=0;c<4;c++) {                                                   \
      int r  = (c<<5) + sr;                                                   \
      int ss = sslot ^ (r & 7);                                               \
      gload16(Ag + (size_t)r*NTOK + ((KT)<<6) + (ss<<3),                      \
              (char*)(LA) + (c<<12) + (wave<<10));                            \
    }                                                                         \
    _Pragma("unroll")                                                         \
    for (int c=0;c<2;c++) {                                                   \
      int r  = (c<<5) + sr;                                                   \
      int ss = sslot ^ (r & 7);                                               \
      gload16(Bg + (size_t)r*NTOK + ((KT)<<6) + (ss<<3),                      \
              (char*)(LB) + (c<<12) + (wave<<10));                            \
    }                                                                         \
  }

#define COMP_PV(LA, LB)                                                       \
  {                                                                           \
    _Pragma("unroll")                                                         \
    for (int ks=0;ks<2;ks++) {                                                \
      half8 af[4], bf[2];                                                     \
      const int kg = lane >> 4;                                               \
      const int rl = lane & 15;                                               \
      const int slot = (ks<<2) + kg;                                          \
      _Pragma("unroll")                                                       \
      for (int t=0;t<4;t++) {                                                 \
        int ar = (wm<<6) + (t<<4) + rl;                                       \
        af[t] = *(const half8*)&(LA)[ar*64 + ((slot ^ (ar&7))<<3)];           \
      }                                                                       \
      _Pragma("unroll")                                                       \
      for (int t=0;t<2;t++) {                                                 \
        int br = (wn<<5) + (t<<4) + rl;                                       \
        bf[t] = *(const half8*)&(LB)[br*64 + ((slot ^ (br&7))<<3)];           \
      }                                                                       \
      _Pragma("unroll")                                                       \
      for (int mt=0;mt<4;mt++)                                                \
        _Pragma("unroll")                                                     \
        for (int nt=0;nt<2;nt++)                                              \
          acc[mt][nt] = __builtin_amdgcn_mfma_f32_16x16x32_f16(af[mt], bf[nt], acc[mt][nt], 0,0,0); \
    }                                                                         \
  }

#define PV_ITER(LA, LB, VM, TS)                                               \
  WAITV(VM); RBAR(); SCHED0();                                                \
  COMP_PV(LA, LB);                                                            \
  RBAR(); SCHED0();                                                           \
  if ((TS) < 64) STAGE_PV(LA, LB, TS);

__global__ __launch_bounds__(256) void pv_gemm(
    const u16* __restrict__ Vc, const u16* __restrict__ Wd,
    float* __restrict__ out, int b_base, size_t wstride)
{
  __shared__ __align__(16) short lds_a0[128*64];   // 16 KB x2
  __shared__ __align__(16) short lds_a1[128*64];
  __shared__ __align__(16) short lds_b0[64*64];    //  8 KB x2
  __shared__ __align__(16) short lds_b1[64*64];
  const int tid  = threadIdx.x;
  const int lane = tid & 63;
  const int wave = tid >> 6;
  const int wm = wave >> 1, wn = wave & 1;
  const int b    = b_base + blockIdx.z;
  const int brow = blockIdx.x << 7;      // channel tile (0/128)
  const int bcol = blockIdx.y << 6;      // token tile (64-wide)

  const u16* Ag = Vc + (size_t)b*CH*NTOK + (size_t)brow*NTOK;
  const u16* Bg = Wd + (size_t)blockIdx.z*wstride + (size_t)bcol*NTOK;

  f32x4 acc[4][2];
  #pragma unroll
  for (int i=0;i<4;i++)
    #pragma unroll
    for (int j=0;j<2;j++) acc[i][j] = (f32x4)0.f;

  const int sr    = tid >> 3;
  const int sslot = tid & 7;

  STAGE_PV(lds_a0, lds_b0, 0);
  STAGE_PV(lds_a1, lds_b1, 1);

  for (int g=0; g<31; ++g) {               // t = 0..61
    const int t = g*2;
    PV_ITER(lds_a0, lds_b0, "vmcnt(6)", t+2);
    PV_ITER(lds_a1, lds_b1, "vmcnt(6)", t+3);
  }
  // tail: t=62, t=63
  WAITV("vmcnt(6)"); RBAR(); SCHED0();
  COMP_PV(lds_a0, lds_b0);
  RBAR(); SCHED0();
  WAITV("vmcnt(0)"); RBAR(); SCHED0();
  COMP_PV(lds_a1, lds_b1);

  float* ob = out + (size_t)b*CH*NTOK;
  const int rl = lane & 15, rg = lane >> 4;
  #pragma unroll
  for (int mt=0;mt<4;mt++) {
    #pragma unroll
    for (int nt=0;nt<2;nt++) {
      int row = brow + (wm<<6) + (mt<<4) + (rg<<2);   // channel
      int col = bcol + (wn<<5) + (nt<<4) + rl;        // token
      #pragma unroll
      for (int r=0;r<4;r++)
        ob[(size_t)(row+r)*NTOK + col] = acc[mt][nt][r];
    }
  }
}

// ---------------- launcher ----------------
extern "C" void kernel_launch(void* const* d_in, const int* in_sizes, int n_in,
                              void* d_out, int out_size, void* d_ws, size_t ws_size,
                              hipStream_t stream)
{
  (void)in_sizes; (void)n_in; (void)out_size;
  const float* x  = (const float*)d_in[0];
  const float* Wq = (const float*)d_in[1];
  const float* Wk = (const float*)d_in[2];
  const float* Wv = (const float*)d_in[3];
  float* out = (float*)d_out;

  char* ws = (char*)d_ws;
  size_t off = 0;
  const size_t plane = (size_t)BATCH*NTOK*CH*2;       // 8.4 MB fp16 plane
  const size_t NN    = (size_t)NTOK*NTOK;             // 16.8M elements
  u16* Qh = (u16*)(ws + off); off += plane;
  u16* Kh = (u16*)(ws + off); off += plane;
  u16* Vc = (u16*)(ws + off); off += plane;
  u16* W3h = (u16*)(ws + off); off += (size_t)3*CH*CH*2;
  u16* W3l = (u16*)(ws + off); off += (size_t)3*CH*CH*2;
  // xT planes live only until proj_gemm completes; S (== W, in-place) overlaps them after.
  const size_t xt_base = off;
  u16* xTh = (u16*)(ws + xt_base);
  u16* xTl = (u16*)(ws + xt_base + plane);
  u16* S   = (u16*)(ws + xt_base);
  const size_t full_need = xt_base + (size_t)BATCH*NN*2;   // ~160 MiB: S[4] fp16, W aliases S
  const bool full = ws_size >= full_need;

  wsplit_kernel<<<dim3(64,3), 256, 0, stream>>>(Wq, Wk, Wv, W3h, W3l);
  xsplit_kernel<<<dim3(64,4,4), 256, 0, stream>>>(x, xTh, xTl);
  proj_gemm<<<dim3(32,2,12), 256, 0, stream>>>(xTh, xTl, W3h, W3l, Qh, Kh, Vc);

  if (full) {
    // all scores -> all selects (in-place S->W) -> pv ; last-touched 134MB = W -> L3-hot for pv
    score_kernel<<<dim3(32,32,4), 256, 0, stream>>>(Qh, Kh, S, 0, NN);
    select_kernel<<<dim3(1024,4), 256, 0, stream>>>(S, NN);
    pv_gemm<<<dim3(2,64,4), 256, 0, stream>>>(Vc, S, out, 0, NN);
  } else {
    // low-ws fallback: per-batch, single S buffer (33.5 MB), still in-place
    for (int b=0; b<BATCH; b++) {
      score_kernel<<<dim3(32,32,1), 256, 0, stream>>>(Qh, Kh, S, b, 0);
      select_kernel<<<dim3(1024,1), 256, 0, stream>>>(S, 0);
      pv_gemm<<<dim3(2,64,1), 256, 0, stream>>>(Vc, S, out, b, 0);
    }
  }
}

// Round 19
// 237.266 us; speedup vs baseline: 1.1735x; 1.1735x over previous
//
#include <hip/hip_runtime.h>
#include <stdint.h>

#define BATCH 4
#define CH    256
#define NTOK  4096
#define KSEL  409          // int(0.1 * 4096)

typedef unsigned short u16;
typedef unsigned int   u32;
typedef unsigned long long u64;

typedef __attribute__((ext_vector_type(8))) _Float16 half8;
typedef __attribute__((ext_vector_type(4))) _Float16 half4;
typedef __attribute__((ext_vector_type(4))) float f32x4;
typedef __attribute__((ext_vector_type(4))) u32 u32x4;
typedef __attribute__((ext_vector_type(2))) u32 u32x2;
typedef __attribute__((ext_vector_type(4))) float fl4;

// ---------------- helpers ----------------
__device__ inline u16 h2u(_Float16 h){ u16 u; __builtin_memcpy(&u,&h,2); return u; }
__device__ inline float u2f16(u32 v){ _Float16 h; u16 uu=(u16)v; __builtin_memcpy(&h,&uu,2); return (float)h; }
// monotone 16-bit fp16<->uint key transform (ascending)
__device__ inline float kinv16(u32 k){
  u32 v = (k & 0x8000u) ? (k & 0x7FFFu) : ((~k) & 0xFFFFu);
  return u2f16(v);
}
__device__ inline u32 ktf16(u32 a){
  return (a & 0x8000u) ? ((~a) & 0xFFFFu) : (a | 0x8000u);
}
__device__ inline void gload16(const void* g, void* l){
  __builtin_amdgcn_global_load_lds((const __attribute__((address_space(1))) u32*)g,
                                   (__attribute__((address_space(3))) u32*)l, 16, 0, 0);
}
// scan a 256-bin per-wave histogram: returns enc = digit<<22 | binCount<<9 | remK
__device__ inline u32 hist_scan(const u32* histw, int lane, u32 kr){
  u32x4 h = *(const u32x4*)&histw[lane<<2];
  u32 tot = h[0]+h[1]+h[2]+h[3];
  u32 sfx = tot;
  #pragma unroll
  for (int off=1; off<64; off<<=1) {
    u32 v = __shfl_down(sfx, off, 64);
    if (lane + off < 64) sfx += v;
  }
  u32 s3 = (sfx - tot) + h[3];
  u32 s2 = s3 + h[2];
  u32 s1 = s2 + h[1];
  u32 s0 = s1 + h[0];
  u32 s4 = s3 - h[3];
  u32 enc = 0;
  if (s0 >= kr && s1 < kr) enc = ((u32)((lane<<2)+0)<<22) | (h[0]<<9) | (kr - s1);
  if (s1 >= kr && s2 < kr) enc = ((u32)((lane<<2)+1)<<22) | (h[1]<<9) | (kr - s2);
  if (s2 >= kr && s3 < kr) enc = ((u32)((lane<<2)+2)<<22) | (h[2]<<9) | (kr - s3);
  if (s3 >= kr && s4 < kr) enc = ((u32)((lane<<2)+3)<<22) | (h[3]<<9) | (kr - s4);
  #pragma unroll
  for (int off=32; off; off>>=1) { u32 o = __shfl_xor(enc, off, 64); enc = (o>enc)? o:enc; }
  return enc;
}

// ---------------- phase -1: W split ----------------
__global__ __launch_bounds__(256) void wsplit_kernel(
    const float* __restrict__ Wq, const float* __restrict__ Wk,
    const float* __restrict__ Wv, u16* __restrict__ W3h, u16* __restrict__ W3l)
{
  const int p = blockIdx.y;
  const float* W = (p==0)? Wq : (p==1)? Wk : Wv;
  const int idx = (blockIdx.x*256 + threadIdx.x) * 4;
  fl4 v = *(const fl4*)(W + idx);
  u32x2 vh, vl;
  #pragma unroll
  for (int q=0;q<2;q++) {
    _Float16 h0=(_Float16)v[q*2], h1=(_Float16)v[q*2+1];
    _Float16 l0=(_Float16)(v[q*2]-(float)h0), l1=(_Float16)(v[q*2+1]-(float)h1);
    vh[q] = (u32)h2u(h0) | ((u32)h2u(h1)<<16);
    vl[q] = (u32)h2u(l0) | ((u32)h2u(l1)<<16);
  }
  *(u32x2*)(W3h + p*CH*CH + idx) = vh;
  *(u32x2*)(W3l + p*CH*CH + idx) = vl;
}

// ---------------- phase 0a: x transpose + split ----------------
__global__ __launch_bounds__(256) void xsplit_kernel(
    const float* __restrict__ x, u16* __restrict__ xTh, u16* __restrict__ xTl)
{
  __shared__ float lds[64][65];
  const int tid = threadIdx.x;
  const int n0 = blockIdx.x << 6;
  const int c0 = blockIdx.y << 6;
  const int b  = blockIdx.z;
  const float* xb = x + (size_t)b*CH*NTOK;

  #pragma unroll
  for (int i=0;i<16;i++) {
    int c_l = (tid>>6) + (i<<2);
    int n_l = tid & 63;
    lds[c_l][n_l] = xb[(size_t)(c0+c_l)*NTOK + n0 + n_l];
  }
  __syncthreads();
  u16* oh = xTh + (size_t)b*NTOK*CH;
  u16* ol = xTl + (size_t)b*NTOK*CH;
  #pragma unroll
  for (int i=0;i<16;i++) {
    int n_l = (tid>>6) + (i<<2);
    int c_l = tid & 63;
    float v = lds[c_l][n_l];
    _Float16 h = (_Float16)v;
    _Float16 l = (_Float16)(v - (float)h);
    size_t o = (size_t)(n0+n_l)*CH + c0 + c_l;
    oh[o] = h2u(h);
    ol[o] = h2u(l);
  }
}

// ---------------- phase 0b: QKV projection GEMM ----------------
__global__ __launch_bounds__(256) void proj_gemm(
    const u16* __restrict__ xTh, const u16* __restrict__ xTl,
    const u16* __restrict__ W3h, const u16* __restrict__ W3l,
    u16* __restrict__ Qh, u16* __restrict__ Kh, u16* __restrict__ Vc)
{
  __shared__ __align__(16) short lds[4*128*64];   // ah, al, bh, bl (16KB each)
  short* lds_ah = lds;
  short* lds_al = lds + 128*64;
  short* lds_bh = lds + 2*128*64;
  short* lds_bl = lds + 3*128*64;

  const int tid  = threadIdx.x;
  const int lane = tid & 63;
  const int wave = tid >> 6;
  const int wm = wave >> 1, wn = wave & 1;
  const int brow = blockIdx.x << 7;     // token tile
  const int bcol = blockIdx.y << 7;     // out-channel tile
  const int z = blockIdx.z;             // b*3 + p
  const int b = z / 3, p = z - 3*b;

  const u16* Agh = xTh + ((size_t)b*NTOK + brow)*CH;
  const u16* Agl = xTl + ((size_t)b*NTOK + brow)*CH;
  const u16* Bgh = W3h + (size_t)p*CH*CH + (size_t)bcol*CH;
  const u16* Bgl = W3l + (size_t)p*CH*CH + (size_t)bcol*CH;

  f32x4 acc[4][4];
  #pragma unroll
  for (int i=0;i<4;i++)
    #pragma unroll
    for (int j=0;j<4;j++) acc[i][j] = (f32x4)0.f;

  const int sr    = tid >> 3;
  const int sslot = tid & 7;

  for (int kt=0; kt<4; kt++) {
    #pragma unroll
    for (int c=0;c<4;c++) {
      int r  = (c<<5) + sr;
      int ss = sslot ^ (r & 7);
      size_t goff = (size_t)r*CH + (kt<<6) + (ss<<3);
      int dst = (c<<12) + (wave<<10);
      gload16(Agh + goff, (char*)lds_ah + dst);
      gload16(Agl + goff, (char*)lds_al + dst);
      gload16(Bgh + goff, (char*)lds_bh + dst);
      gload16(Bgl + goff, (char*)lds_bl + dst);
    }
    __syncthreads();
    #pragma unroll
    for (int ks=0;ks<2;ks++) {
      half8 ah[4], al[4], bh[4], bl[4];
      const int kg = lane >> 4;
      const int rl = lane & 15;
      #pragma unroll
      for (int t=0;t<4;t++) {
        int ar = (wm<<6) + (t<<4) + rl;
        int slot = (ks<<2) + kg;
        int ao = ar*64 + ((slot ^ (ar&7))<<3);
        ah[t] = *(const half8*)&lds_ah[ao];
        al[t] = *(const half8*)&lds_al[ao];
        int br = (wn<<6) + (t<<4) + rl;
        int bo = br*64 + ((slot ^ (br&7))<<3);
        bh[t] = *(const half8*)&lds_bh[bo];
        bl[t] = *(const half8*)&lds_bl[bo];
      }
      #pragma unroll
      for (int mt=0;mt<4;mt++)
        #pragma unroll
        for (int nt=0;nt<4;nt++) {
          acc[mt][nt] = __builtin_amdgcn_mfma_f32_16x16x32_f16(ah[mt], bh[nt], acc[mt][nt], 0,0,0);
          acc[mt][nt] = __builtin_amdgcn_mfma_f32_16x16x32_f16(ah[mt], bl[nt], acc[mt][nt], 0,0,0);
          acc[mt][nt] = __builtin_amdgcn_mfma_f32_16x16x32_f16(al[mt], bh[nt], acc[mt][nt], 0,0,0);
        }
    }
    __syncthreads();
  }

  const int rl = lane & 15, rg = lane >> 4;
  if (p < 2) {
    u16* oh = ((p==0)? Qh : Kh) + (size_t)b*NTOK*CH;
    #pragma unroll
    for (int mt=0;mt<4;mt++) {
      #pragma unroll
      for (int nt=0;nt<4;nt++) {
        int n = brow + (wm<<6) + (mt<<4) + (rg<<2);
        int c = bcol + (wn<<6) + (nt<<4) + rl;
        #pragma unroll
        for (int r=0;r<4;r++)
          oh[(size_t)(n+r)*CH + c] = h2u((_Float16)acc[mt][nt][r]);
      }
    }
  } else {
    // V: transpose in LDS -> store channel-major Vc[b][d][n] coalesced
    u16* ldsT = (u16*)lds;                 // [128][136] u16
    #pragma unroll
    for (int mt=0;mt<4;mt++) {
      #pragma unroll
      for (int nt=0;nt<4;nt++) {
        int n_l = (wm<<6) + (mt<<4) + (rg<<2);
        int c_l = (wn<<6) + (nt<<4) + rl;
        half4 hv;
        #pragma unroll
        for (int r=0;r<4;r++) hv[r] = (_Float16)acc[mt][nt][r];
        *(half4*)&ldsT[c_l*136 + n_l] = hv;
      }
    }
    __syncthreads();
    u16* ov = Vc + (size_t)b*CH*NTOK + (size_t)bcol*NTOK + brow;
    #pragma unroll
    for (int i=0;i<32;i++) {
      int d_l = (tid>>6) + (i<<2);
      u32 v = *(const u32*)&ldsT[d_l*136 + (lane<<1)];
      *(u32*)(ov + (size_t)d_l*NTOK + (lane<<1)) = v;
    }
  }
}

// ============ counted-vmcnt pipeline macros (T4: never drain vmcnt to 0 mid-loop) ============
#define WAITV(S)  asm volatile("s_waitcnt " S ::: "memory")
#define RBAR()    __builtin_amdgcn_s_barrier()
#define SCHED0()  __builtin_amdgcn_sched_barrier(0)

// ---------------- phase 1: S = Q*K^T / 16, hi-only fp16, fp16 out, 2-deep pipeline ----------------
#define STAGE_SC(LA, LB, KT)                                                  \
  {                                                                           \
    _Pragma("unroll")                                                         \
    for (int c=0;c<4;c++) {                                                   \
      int r  = (c<<5) + sr;                                                   \
      int ss = sslot ^ (r & 7);                                               \
      size_t goff = (size_t)r*CH + ((KT)<<6) + (ss<<3);                       \
      gload16(Ag + goff, (char*)(LA) + (c<<12) + (wave<<10));                 \
      gload16(Bg + goff, (char*)(LB) + (c<<12) + (wave<<10));                 \
    }                                                                         \
  }

#define COMP_SC(LA, LB)                                                       \
  {                                                                           \
    _Pragma("unroll")                                                         \
    for (int ks=0;ks<2;ks++) {                                                \
      half8 af[4], bf[4];                                                     \
      const int kg = lane >> 4;                                               \
      const int rl = lane & 15;                                               \
      _Pragma("unroll")                                                       \
      for (int t=0;t<4;t++) {                                                 \
        int ar = (wm<<6) + (t<<4) + rl;                                       \
        int slot = (ks<<2) + kg;                                              \
        af[t] = *(const half8*)&(LA)[ar*64 + ((slot ^ (ar&7))<<3)];           \
        int br = (wn<<6) + (t<<4) + rl;                                       \
        bf[t] = *(const half8*)&(LB)[br*64 + ((slot ^ (br&7))<<3)];           \
      }                                                                       \
      _Pragma("unroll")                                                       \
      for (int mt=0;mt<4;mt++)                                                \
        _Pragma("unroll")                                                     \
        for (int nt=0;nt<4;nt++)                                              \
          acc[mt][nt] = __builtin_amdgcn_mfma_f32_16x16x32_f16(af[mt], bf[nt], acc[mt][nt], 0,0,0); \
    }                                                                         \
  }

__global__ __launch_bounds__(256) void score_kernel(
    const u16* __restrict__ Qh, const u16* __restrict__ Kh,
    u16* __restrict__ S, int b_base, size_t sstride)
{
  __shared__ __align__(16) short lds_a0[128*64];
  __shared__ __align__(16) short lds_a1[128*64];
  __shared__ __align__(16) short lds_b0[128*64];
  __shared__ __align__(16) short lds_b1[128*64];
  const int tid  = threadIdx.x;
  const int lane = tid & 63;
  const int wave = tid >> 6;
  const int wm = wave >> 1, wn = wave & 1;
  const int brow = blockIdx.x << 7, bcol = blockIdx.y << 7;
  const int b = b_base + blockIdx.z;
  u16* Sb = S + (size_t)blockIdx.z * sstride;

  const u16* Ag = Qh + ((size_t)b*NTOK + brow)*CH;
  const u16* Bg = Kh + ((size_t)b*NTOK + bcol)*CH;

  f32x4 acc[4][4];
  #pragma unroll
  for (int i=0;i<4;i++)
    #pragma unroll
    for (int j=0;j<4;j++) acc[i][j] = (f32x4)0.f;

  const int sr    = tid >> 3;
  const int sslot = tid & 7;

  STAGE_SC(lds_a0, lds_b0, 0);
  STAGE_SC(lds_a1, lds_b1, 1);
  // t=0
  WAITV("vmcnt(8)"); RBAR(); SCHED0();
  COMP_SC(lds_a0, lds_b0);
  RBAR(); SCHED0();
  STAGE_SC(lds_a0, lds_b0, 2);
  // t=1
  WAITV("vmcnt(8)"); RBAR(); SCHED0();
  COMP_SC(lds_a1, lds_b1);
  RBAR(); SCHED0();
  STAGE_SC(lds_a1, lds_b1, 3);
  // t=2
  WAITV("vmcnt(8)"); RBAR(); SCHED0();
  COMP_SC(lds_a0, lds_b0);
  RBAR(); SCHED0();
  // t=3
  WAITV("vmcnt(0)"); RBAR(); SCHED0();
  COMP_SC(lds_a1, lds_b1);

  const int rl = lane & 15, rg = lane >> 4;
  #pragma unroll
  for (int mt=0;mt<4;mt++) {
    #pragma unroll
    for (int nt=0;nt<4;nt++) {
      int row = brow + (wm<<6) + (mt<<4) + (rg<<2);
      int col = bcol + (wn<<6) + (nt<<4) + rl;
      #pragma unroll
      for (int r=0;r<4;r++)
        Sb[(size_t)(row+r)*NTOK + col] = h2u((_Float16)(acc[mt][nt][r] * 0.0625f));
    }
  }
}

// ---------------- phase 2: exact per-row top-KSEL on fp16 scores, IN-PLACE S->W ----------------
// v5: round-14 semantics with keys PACKED 2-per-u32 (key2[32] fits registers; round-14's
// key[64] spilled to scratch at VGPR=56; round-18's streaming reloads missed L2).
// Same histogram+fences, same enc encoding, same fast/slow tie paths in ch order,
// same z accumulation order; write pass recomputes exp (same input+op = same value).
__global__ __launch_bounds__(256) void select_kernel(u16* Sh, size_t sstride)
{
  __shared__ __align__(16) u32 hist[4][256];
  const int lane = threadIdx.x & 63;
  const int wave = threadIdx.x >> 6;
  const int row  = (blockIdx.x << 2) + wave;
  u16* Srow = Sh + (size_t)blockIdx.y * sstride + (size_t)row * NTOK + (lane << 3);

  // load + transform + pack (element pair (2t, 2t+1) -> lo/hi of key2[t])
  u32 key2[32];
  u32 umax = 0;
  #pragma unroll
  for (int g=0; g<8; ++g) {
    u32x4 q = *(const u32x4*)(Srow + (g<<9));   // stripe g: 512 elements
    #pragma unroll
    for (int j=0; j<4; ++j) {
      u32 w = q[j];
      u32 a = ktf16(w & 0xFFFFu), bb = ktf16(w >> 16);
      key2[(g<<2)+j] = a | (bb << 16);
      umax = umax > a  ? umax : a;
      umax = umax > bb ? umax : bb;
    }
  }
  #pragma unroll
  for (int off=32; off; off>>=1) { u32 o = __shfl_xor(umax, off, 64); umax = o>umax ? o : umax; }
  const float m = kinv16(umax);

  // ---- pass 0: high-byte histogram ----
  #pragma unroll
  for (int i=0;i<4;i++) hist[wave][(i<<6)+lane] = 0u;
  __asm__ volatile("s_waitcnt lgkmcnt(0)" ::: "memory");
  #pragma unroll
  for (int t=0; t<32; ++t) {
    u32 w = key2[t];
    atomicAdd(&hist[wave][(w & 0xFFFFu) >> 8], 1u);
    atomicAdd(&hist[wave][w >> 24], 1u);
  }
  __asm__ volatile("s_waitcnt lgkmcnt(0)" ::: "memory");
  u32 enc = hist_scan(hist[wave], lane, KSEL);
  u32 prefix = (enc >> 22) << 8;
  u32 krem   = enc & 0x1FFu;

  // ---- pass 1: low-byte histogram within the threshold high-byte bin ----
  #pragma unroll
  for (int i=0;i<4;i++) hist[wave][(i<<6)+lane] = 0u;
  __asm__ volatile("s_waitcnt lgkmcnt(0)" ::: "memory");
  const u32 b1 = prefix >> 8;
  #pragma unroll
  for (int t=0; t<32; ++t) {
    u32 w = key2[t];
    u32 a = w & 0xFFFFu, bb = w >> 16;
    if ((a  >> 8) == b1) atomicAdd(&hist[wave][a  & 255u], 1u);
    if ((bb >> 8) == b1) atomicAdd(&hist[wave][bb & 255u], 1u);
  }
  __asm__ volatile("s_waitcnt lgkmcnt(0)" ::: "memory");
  enc = hist_scan(hist[wave], lane, krem);
  prefix |= (enc >> 22);
  const u32 cb = (enc >> 9) & 0x1FFFu;
  krem = enc & 0x1FFu;
  const u32 tkey = prefix;                    // exact KSEL-th-largest fp16 key

  // selection bitmask (fast: all ties included; slow: ballot-ordered in ch order)
  u64 selb = 0;
  if (cb == krem) {
    #pragma unroll
    for (int t=0; t<32; ++t) {
      u32 w = key2[t];
      if ((w & 0xFFFFu) >= tkey) selb |= (1ull << (2*t));
      if ((w >> 16)     >= tkey) selb |= (2ull << (2*t));
    }
  } else {
    const u64 ltmask = (1ull << lane) - 1ull;
    int eqbase = 0;
    #pragma unroll
    for (int t=0; t<32; ++t) {
      u32 w = key2[t];
      #pragma unroll
      for (int hh=0; hh<2; ++hh) {
        u32 k = hh ? (w >> 16) : (w & 0xFFFFu);
        bool eq = (k == tkey);
        u64 eqm = __ballot(eq);
        bool sel = (k > tkey) || (eq && (eqbase + __popcll(eqm & ltmask)) < (int)krem);
        if (sel) selb |= (1ull << (2*t+hh));
        eqbase += __popcll(eqm);
      }
    }
  }

  // z pass: exp in ch order, accumulate over selected
  float z = 0.f;
  #pragma unroll
  for (int t=0; t<32; ++t) {
    u32 w = key2[t];
    float e0 = __expf(kinv16(w & 0xFFFFu) - m);
    float e1 = __expf(kinv16(w >> 16) - m);
    if ((selb >> (2*t)) & 1ull) z += e0;
    if ((selb >> (2*t+1)) & 1ull) z += e1;
  }
  #pragma unroll
  for (int off=32; off; off>>=1) z += __shfl_xor(z, off, 64);
  const float invZ = 1.f / z;

  // write pass: recompute exp (same input+op = identical value), scale, pack, store
  #pragma unroll
  for (int g=0; g<8; ++g) {
    u32x4 v;
    #pragma unroll
    for (int j=0; j<4; ++j) {
      u32 w = key2[(g<<2)+j];
      int i0 = (g<<3)+(j<<1);
      float w0 = ((selb >> i0) & 1ull) ? __expf(kinv16(w & 0xFFFFu) - m) * invZ : 0.f;
      float w1 = ((selb >> (i0+1)) & 1ull) ? __expf(kinv16(w >> 16) - m) * invZ : 0.f;
      v[j] = (u32)h2u((_Float16)w0) | ((u32)h2u((_Float16)w1) << 16);
    }
    *(u32x4*)(Srow + (g<<9)) = v;
  }
}

// ---------------- phase 3: dense PV GEMM, 2-deep counted-vmcnt pipeline ----------------
// out^T[c,n] = sum_k Vc[c,k] * Wd[n,k].  128(M=ch) x 64(N=tok) tiles, K=NTOK, BK=64.
// Wd aliases S: freshly rewritten by select -> L3-resident at launch.
#define STAGE_PV(LA, LB, KT)                                                  \
  {                                                                           \
    _Pragma("unroll")                                                         \
    for (int c=0;c<4;c++) {                                                   \
      int r  = (c<<5) + sr;                                                   \
      int ss = sslot ^ (r & 7);                                               \
      gload16(Ag + (size_t)r*NTOK + ((KT)<<6) + (ss<<3),                      \
              (char*)(LA) + (c<<12) + (wave<<10));                            \
    }                                                                         \
    _Pragma("unroll")                                                         \
    for (int c=0;c<2;c++) {                                                   \
      int r  = (c<<5) + sr;                                                   \
      int ss = sslot ^ (r & 7);                                               \
      gload16(Bg + (size_t)r*NTOK + ((KT)<<6) + (ss<<3),                      \
              (char*)(LB) + (c<<12) + (wave<<10));                            \
    }                                                                         \
  }

#define COMP_PV(LA, LB)                                                       \
  {                                                                           \
    _Pragma("unroll")                                                         \
    for (int ks=0;ks<2;ks++) {                                                \
      half8 af[4], bf[2];                                                     \
      const int kg = lane >> 4;                                               \
      const int rl = lane & 15;                                               \
      const int slot = (ks<<2) + kg;                                          \
      _Pragma("unroll")                                                       \
      for (int t=0;t<4;t++) {                                                 \
        int ar = (wm<<6) + (t<<4) + rl;                                       \
        af[t] = *(const half8*)&(LA)[ar*64 + ((slot ^ (ar&7))<<3)];           \
      }                                                                       \
      _Pragma("unroll")                                                       \
      for (int t=0;t<2;t++) {                                                 \
        int br = (wn<<5) + (t<<4) + rl;                                       \
        bf[t] = *(const half8*)&(LB)[br*64 + ((slot ^ (br&7))<<3)];           \
      }                                                                       \
      _Pragma("unroll")                                                       \
      for (int mt=0;mt<4;mt++)                                                \
        _Pragma("unroll")                                                     \
        for (int nt=0;nt<2;nt++)                                              \
          acc[mt][nt] = __builtin_amdgcn_mfma_f32_16x16x32_f16(af[mt], bf[nt], acc[mt][nt], 0,0,0); \
    }                                                                         \
  }

#define PV_ITER(LA, LB, VM, TS)                                               \
  WAITV(VM); RBAR(); SCHED0();                                                \
  COMP_PV(LA, LB);                                                            \
  RBAR(); SCHED0();                                                           \
  if ((TS) < 64) STAGE_PV(LA, LB, TS);

__global__ __launch_bounds__(256) void pv_gemm(
    const u16* __restrict__ Vc, const u16* __restrict__ Wd,
    float* __restrict__ out, int b_base, size_t wstride)
{
  __shared__ __align__(16) short lds_a0[128*64];   // 16 KB x2
  __shared__ __align__(16) short lds_a1[128*64];
  __shared__ __align__(16) short lds_b0[64*64];    //  8 KB x2
  __shared__ __align__(16) short lds_b1[64*64];
  const int tid  = threadIdx.x;
  const int lane = tid & 63;
  const int wave = tid >> 6;
  const int wm = wave >> 1, wn = wave & 1;
  const int b    = b_base + blockIdx.z;
  const int brow = blockIdx.x << 7;      // channel tile (0/128)
  const int bcol = blockIdx.y << 6;      // token tile (64-wide)

  const u16* Ag = Vc + (size_t)b*CH*NTOK + (size_t)brow*NTOK;
  const u16* Bg = Wd + (size_t)blockIdx.z*wstride + (size_t)bcol*NTOK;

  f32x4 acc[4][2];
  #pragma unroll
  for (int i=0;i<4;i++)
    #pragma unroll
    for (int j=0;j<2;j++) acc[i][j] = (f32x4)0.f;

  const int sr    = tid >> 3;
  const int sslot = tid & 7;

  STAGE_PV(lds_a0, lds_b0, 0);
  STAGE_PV(lds_a1, lds_b1, 1);

  for (int g=0; g<31; ++g) {               // t = 0..61
    const int t = g*2;
    PV_ITER(lds_a0, lds_b0, "vmcnt(6)", t+2);
    PV_ITER(lds_a1, lds_b1, "vmcnt(6)", t+3);
  }
  // tail: t=62, t=63
  WAITV("vmcnt(6)"); RBAR(); SCHED0();
  COMP_PV(lds_a0, lds_b0);
  RBAR(); SCHED0();
  WAITV("vmcnt(0)"); RBAR(); SCHED0();
  COMP_PV(lds_a1, lds_b1);

  float* ob = out + (size_t)b*CH*NTOK;
  const int rl = lane & 15, rg = lane >> 4;
  #pragma unroll
  for (int mt=0;mt<4;mt++) {
    #pragma unroll
    for (int nt=0;nt<2;nt++) {
      int row = brow + (wm<<6) + (mt<<4) + (rg<<2);   // channel
      int col = bcol + (wn<<5) + (nt<<4) + rl;        // token
      #pragma unroll
      for (int r=0;r<4;r++)
        ob[(size_t)(row+r)*NTOK + col] = acc[mt][nt][r];
    }
  }
}

// ---------------- launcher ----------------
extern "C" void kernel_launch(void* const* d_in, const int* in_sizes, int n_in,
                              void* d_out, int out_size, void* d_ws, size_t ws_size,
                              hipStream_t stream)
{
  (void)in_sizes; (void)n_in; (void)out_size;
  const float* x  = (const float*)d_in[0];
  const float* Wq = (const float*)d_in[1];
  const float* Wk = (const float*)d_in[2];
  const float* Wv = (const float*)d_in[3];
  float* out = (float*)d_out;

  char* ws = (char*)d_ws;
  size_t off = 0;
  const size_t plane = (size_t)BATCH*NTOK*CH*2;       // 8.4 MB fp16 plane
  const size_t NN    = (size_t)NTOK*NTOK;             // 16.8M elements
  u16* Qh = (u16*)(ws + off); off += plane;
  u16* Kh = (u16*)(ws + off); off += plane;
  u16* Vc = (u16*)(ws + off); off += plane;
  u16* W3h = (u16*)(ws + off); off += (size_t)3*CH*CH*2;
  u16* W3l = (u16*)(ws + off); off += (size_t)3*CH*CH*2;
  // xT planes live only until proj_gemm completes; S (== W, in-place) overlaps them after.
  const size_t xt_base = off;
  u16* xTh = (u16*)(ws + xt_base);
  u16* xTl = (u16*)(ws + xt_base + plane);
  u16* S   = (u16*)(ws + xt_base);
  const size_t full_need = xt_base + (size_t)BATCH*NN*2;   // ~160 MiB: S[4] fp16, W aliases S
  const bool full = ws_size >= full_need;

  wsplit_kernel<<<dim3(64,3), 256, 0, stream>>>(Wq, Wk, Wv, W3h, W3l);
  xsplit_kernel<<<dim3(64,4,4), 256, 0, stream>>>(x, xTh, xTl);
  proj_gemm<<<dim3(32,2,12), 256, 0, stream>>>(xTh, xTl, W3h, W3l, Qh, Kh, Vc);

  if (full) {
    // all scores -> all selects (in-place S->W) -> pv ; last-touched 134MB = W -> L3-hot for pv
    score_kernel<<<dim3(32,32,4), 256, 0, stream>>>(Qh, Kh, S, 0, NN);
    select_kernel<<<dim3(1024,4), 256, 0, stream>>>(S, NN);
    pv_gemm<<<dim3(2,64,4), 256, 0, stream>>>(Vc, S, out, 0, NN);
  } else {
    // low-ws fallback: per-batch, single S buffer (33.5 MB), still in-place
    for (int b=0; b<BATCH; b++) {
      score_kernel<<<dim3(32,32,1), 256, 0, stream>>>(Qh, Kh, S, b, 0);
      select_kernel<<<dim3(1024,1), 256, 0, stream>>>(S, 0);
      pv_gemm<<<dim3(2,64,1), 256, 0, stream>>>(Vc, S, out, b, 0);
    }
  }
}

// Round 20
// 228.165 us; speedup vs baseline: 1.2203x; 1.0399x over previous
//
#include <hip/hip_runtime.h>
#include <stdint.h>

#define BATCH 4
#define CH    256
#define NTOK  4096
#define KSEL  409          // int(0.1 * 4096)

typedef unsigned short u16;
typedef unsigned int   u32;
typedef unsigned long long u64;

typedef __attribute__((ext_vector_type(8))) _Float16 half8;
typedef __attribute__((ext_vector_type(4))) _Float16 half4;
typedef __attribute__((ext_vector_type(4))) float f32x4;
typedef __attribute__((ext_vector_type(4))) u32 u32x4;
typedef __attribute__((ext_vector_type(2))) u32 u32x2;
typedef __attribute__((ext_vector_type(4))) float fl4;

// ---------------- helpers ----------------
__device__ inline u16 h2u(_Float16 h){ u16 u; __builtin_memcpy(&u,&h,2); return u; }
__device__ inline float u2f16(u32 v){ _Float16 h; u16 uu=(u16)v; __builtin_memcpy(&h,&uu,2); return (float)h; }
// monotone 16-bit fp16<->uint key transform (ascending)
__device__ inline float kinv16(u32 k){
  u32 v = (k & 0x8000u) ? (k & 0x7FFFu) : ((~k) & 0xFFFFu);
  return u2f16(v);
}
__device__ inline void gload16(const void* g, void* l){
  __builtin_amdgcn_global_load_lds((const __attribute__((address_space(1))) u32*)g,
                                   (__attribute__((address_space(3))) u32*)l, 16, 0, 0);
}

// ---------------- phase -1: W split ----------------
__global__ __launch_bounds__(256) void wsplit_kernel(
    const float* __restrict__ Wq, const float* __restrict__ Wk,
    const float* __restrict__ Wv, u16* __restrict__ W3h, u16* __restrict__ W3l)
{
  const int p = blockIdx.y;
  const float* W = (p==0)? Wq : (p==1)? Wk : Wv;
  const int idx = (blockIdx.x*256 + threadIdx.x) * 4;
  fl4 v = *(const fl4*)(W + idx);
  u32x2 vh, vl;
  #pragma unroll
  for (int q=0;q<2;q++) {
    _Float16 h0=(_Float16)v[q*2], h1=(_Float16)v[q*2+1];
    _Float16 l0=(_Float16)(v[q*2]-(float)h0), l1=(_Float16)(v[q*2+1]-(float)h1);
    vh[q] = (u32)h2u(h0) | ((u32)h2u(h1)<<16);
    vl[q] = (u32)h2u(l0) | ((u32)h2u(l1)<<16);
  }
  *(u32x2*)(W3h + p*CH*CH + idx) = vh;
  *(u32x2*)(W3l + p*CH*CH + idx) = vl;
}

// ---------------- phase 0a: x transpose + split ----------------
__global__ __launch_bounds__(256) void xsplit_kernel(
    const float* __restrict__ x, u16* __restrict__ xTh, u16* __restrict__ xTl)
{
  __shared__ float lds[64][65];
  const int tid = threadIdx.x;
  const int n0 = blockIdx.x << 6;
  const int c0 = blockIdx.y << 6;
  const int b  = blockIdx.z;
  const float* xb = x + (size_t)b*CH*NTOK;

  #pragma unroll
  for (int i=0;i<16;i++) {
    int c_l = (tid>>6) + (i<<2);
    int n_l = tid & 63;
    lds[c_l][n_l] = xb[(size_t)(c0+c_l)*NTOK + n0 + n_l];
  }
  __syncthreads();
  u16* oh = xTh + (size_t)b*NTOK*CH;
  u16* ol = xTl + (size_t)b*NTOK*CH;
  #pragma unroll
  for (int i=0;i<16;i++) {
    int n_l = (tid>>6) + (i<<2);
    int c_l = tid & 63;
    float v = lds[c_l][n_l];
    _Float16 h = (_Float16)v;
    _Float16 l = (_Float16)(v - (float)h);
    size_t o = (size_t)(n0+n_l)*CH + c0 + c_l;
    oh[o] = h2u(h);
    ol[o] = h2u(l);
  }
}

// ---------------- phase 0b: QKV projection GEMM ----------------
__global__ __launch_bounds__(256) void proj_gemm(
    const u16* __restrict__ xTh, const u16* __restrict__ xTl,
    const u16* __restrict__ W3h, const u16* __restrict__ W3l,
    u16* __restrict__ Qh, u16* __restrict__ Kh, u16* __restrict__ Vc)
{
  __shared__ __align__(16) short lds[4*128*64];   // ah, al, bh, bl (16KB each)
  short* lds_ah = lds;
  short* lds_al = lds + 128*64;
  short* lds_bh = lds + 2*128*64;
  short* lds_bl = lds + 3*128*64;

  const int tid  = threadIdx.x;
  const int lane = tid & 63;
  const int wave = tid >> 6;
  const int wm = wave >> 1, wn = wave & 1;
  const int brow = blockIdx.x << 7;     // token tile
  const int bcol = blockIdx.y << 7;     // out-channel tile
  const int z = blockIdx.z;             // b*3 + p
  const int b = z / 3, p = z - 3*b;

  const u16* Agh = xTh + ((size_t)b*NTOK + brow)*CH;
  const u16* Agl = xTl + ((size_t)b*NTOK + brow)*CH;
  const u16* Bgh = W3h + (size_t)p*CH*CH + (size_t)bcol*CH;
  const u16* Bgl = W3l + (size_t)p*CH*CH + (size_t)bcol*CH;

  f32x4 acc[4][4];
  #pragma unroll
  for (int i=0;i<4;i++)
    #pragma unroll
    for (int j=0;j<4;j++) acc[i][j] = (f32x4)0.f;

  const int sr    = tid >> 3;
  const int sslot = tid & 7;

  for (int kt=0; kt<4; kt++) {
    #pragma unroll
    for (int c=0;c<4;c++) {
      int r  = (c<<5) + sr;
      int ss = sslot ^ (r & 7);
      size_t goff = (size_t)r*CH + (kt<<6) + (ss<<3);
      int dst = (c<<12) + (wave<<10);
      gload16(Agh + goff, (char*)lds_ah + dst);
      gload16(Agl + goff, (char*)lds_al + dst);
      gload16(Bgh + goff, (char*)lds_bh + dst);
      gload16(Bgl + goff, (char*)lds_bl + dst);
    }
    __syncthreads();
    #pragma unroll
    for (int ks=0;ks<2;ks++) {
      half8 ah[4], al[4], bh[4], bl[4];
      const int kg = lane >> 4;
      const int rl = lane & 15;
      #pragma unroll
      for (int t=0;t<4;t++) {
        int ar = (wm<<6) + (t<<4) + rl;
        int slot = (ks<<2) + kg;
        int ao = ar*64 + ((slot ^ (ar&7))<<3);
        ah[t] = *(const half8*)&lds_ah[ao];
        al[t] = *(const half8*)&lds_al[ao];
        int br = (wn<<6) + (t<<4) + rl;
        int bo = br*64 + ((slot ^ (br&7))<<3);
        bh[t] = *(const half8*)&lds_bh[bo];
        bl[t] = *(const half8*)&lds_bl[bo];
      }
      #pragma unroll
      for (int mt=0;mt<4;mt++)
        #pragma unroll
        for (int nt=0;nt<4;nt++) {
          acc[mt][nt] = __builtin_amdgcn_mfma_f32_16x16x32_f16(ah[mt], bh[nt], acc[mt][nt], 0,0,0);
          acc[mt][nt] = __builtin_amdgcn_mfma_f32_16x16x32_f16(ah[mt], bl[nt], acc[mt][nt], 0,0,0);
          acc[mt][nt] = __builtin_amdgcn_mfma_f32_16x16x32_f16(al[mt], bh[nt], acc[mt][nt], 0,0,0);
        }
    }
    __syncthreads();
  }

  const int rl = lane & 15, rg = lane >> 4;
  if (p < 2) {
    u16* oh = ((p==0)? Qh : Kh) + (size_t)b*NTOK*CH;
    #pragma unroll
    for (int mt=0;mt<4;mt++) {
      #pragma unroll
      for (int nt=0;nt<4;nt++) {
        int n = brow + (wm<<6) + (mt<<4) + (rg<<2);
        int c = bcol + (wn<<6) + (nt<<4) + rl;
        #pragma unroll
        for (int r=0;r<4;r++)
          oh[(size_t)(n+r)*CH + c] = h2u((_Float16)acc[mt][nt][r]);
      }
    }
  } else {
    // V: transpose in LDS -> store channel-major Vc[b][d][n] coalesced
    u16* ldsT = (u16*)lds;                 // [128][136] u16
    #pragma unroll
    for (int mt=0;mt<4;mt++) {
      #pragma unroll
      for (int nt=0;nt<4;nt++) {
        int n_l = (wm<<6) + (mt<<4) + (rg<<2);
        int c_l = (wn<<6) + (nt<<4) + rl;
        half4 hv;
        #pragma unroll
        for (int r=0;r<4;r++) hv[r] = (_Float16)acc[mt][nt][r];
        *(half4*)&ldsT[c_l*136 + n_l] = hv;
      }
    }
    __syncthreads();
    u16* ov = Vc + (size_t)b*CH*NTOK + (size_t)bcol*NTOK + brow;
    #pragma unroll
    for (int i=0;i<32;i++) {
      int d_l = (tid>>6) + (i<<2);
      u32 v = *(const u32*)&ldsT[d_l*136 + (lane<<1)];
      *(u32*)(ov + (size_t)d_l*NTOK + (lane<<1)) = v;
    }
  }
}

// ============ counted-vmcnt pipeline macros (T4: never drain vmcnt to 0 mid-loop) ============
#define WAITV(S)  asm volatile("s_waitcnt " S ::: "memory")
#define RBAR()    __builtin_amdgcn_s_barrier()
#define SCHED0()  __builtin_amdgcn_sched_barrier(0)

// ---------------- phase 1: S = Q*K^T / 16, hi-only fp16, fp16 out, 2-deep pipeline ----------------
#define STAGE_SC(LA, LB, KT)                                                  \
  {                                                                           \
    _Pragma("unroll")                                                         \
    for (int c=0;c<4;c++) {                                                   \
      int r  = (c<<5) + sr;                                                   \
      int ss = sslot ^ (r & 7);                                               \
      size_t goff = (size_t)r*CH + ((KT)<<6) + (ss<<3);                       \
      gload16(Ag + goff, (char*)(LA) + (c<<12) + (wave<<10));                 \
      gload16(Bg + goff, (char*)(LB) + (c<<12) + (wave<<10));                 \
    }                                                                         \
  }

#define COMP_SC(LA, LB)                                                       \
  {                                                                           \
    _Pragma("unroll")                                                         \
    for (int ks=0;ks<2;ks++) {                                                \
      half8 af[4], bf[4];                                                     \
      const int kg = lane >> 4;                                               \
      const int rl = lane & 15;                                               \
      _Pragma("unroll")                                                       \
      for (int t=0;t<4;t++) {                                                 \
        int ar = (wm<<6) + (t<<4) + rl;                                       \
        int slot = (ks<<2) + kg;                                              \
        af[t] = *(const half8*)&(LA)[ar*64 + ((slot ^ (ar&7))<<3)];           \
        int br = (wn<<6) + (t<<4) + rl;                                       \
        bf[t] = *(const half8*)&(LB)[br*64 + ((slot ^ (br&7))<<3)];           \
      }                                                                       \
      _Pragma("unroll")                                                       \
      for (int mt=0;mt<4;mt++)                                                \
        _Pragma("unroll")                                                     \
        for (int nt=0;nt<4;nt++)                                              \
          acc[mt][nt] = __builtin_amdgcn_mfma_f32_16x16x32_f16(af[mt], bf[nt], acc[mt][nt], 0,0,0); \
    }                                                                         \
  }

__global__ __launch_bounds__(256) void score_kernel(
    const u16* __restrict__ Qh, const u16* __restrict__ Kh,
    u16* __restrict__ S, int b_base, size_t sstride)
{
  __shared__ __align__(16) short lds_a0[128*64];
  __shared__ __align__(16) short lds_a1[128*64];
  __shared__ __align__(16) short lds_b0[128*64];
  __shared__ __align__(16) short lds_b1[128*64];
  const int tid  = threadIdx.x;
  const int lane = tid & 63;
  const int wave = tid >> 6;
  const int wm = wave >> 1, wn = wave & 1;
  const int brow = blockIdx.x << 7, bcol = blockIdx.y << 7;
  const int b = b_base + blockIdx.z;
  u16* Sb = S + (size_t)blockIdx.z * sstride;

  const u16* Ag = Qh + ((size_t)b*NTOK + brow)*CH;
  const u16* Bg = Kh + ((size_t)b*NTOK + bcol)*CH;

  f32x4 acc[4][4];
  #pragma unroll
  for (int i=0;i<4;i++)
    #pragma unroll
    for (int j=0;j<4;j++) acc[i][j] = (f32x4)0.f;

  const int sr    = tid >> 3;
  const int sslot = tid & 7;

  STAGE_SC(lds_a0, lds_b0, 0);
  STAGE_SC(lds_a1, lds_b1, 1);
  // t=0
  WAITV("vmcnt(8)"); RBAR(); SCHED0();
  COMP_SC(lds_a0, lds_b0);
  RBAR(); SCHED0();
  STAGE_SC(lds_a0, lds_b0, 2);
  // t=1
  WAITV("vmcnt(8)"); RBAR(); SCHED0();
  COMP_SC(lds_a1, lds_b1);
  RBAR(); SCHED0();
  STAGE_SC(lds_a1, lds_b1, 3);
  // t=2
  WAITV("vmcnt(8)"); RBAR(); SCHED0();
  COMP_SC(lds_a0, lds_b0);
  RBAR(); SCHED0();
  // t=3
  WAITV("vmcnt(0)"); RBAR(); SCHED0();
  COMP_SC(lds_a1, lds_b1);

  const int rl = lane & 15, rg = lane >> 4;
  #pragma unroll
  for (int mt=0;mt<4;mt++) {
    #pragma unroll
    for (int nt=0;nt<4;nt++) {
      int row = brow + (wm<<6) + (mt<<4) + (rg<<2);
      int col = bcol + (wn<<6) + (nt<<4) + rl;
      #pragma unroll
      for (int r=0;r<4;r++)
        Sb[(size_t)(row+r)*NTOK + col] = h2u((_Float16)(acc[mt][nt][r] * 0.0625f));
    }
  }
}

// ---------------- phase 2: exact per-row top-KSEL on fp16 scores, IN-PLACE S->W ----------------
// Round-14 semantics (passed full validation; canary absmax 1.123047e-2) with ONE change:
// 4-copy sub-histograms hist[wave][lane&3][256] to cut hot-bin LDS-atomic serialization /4.
// Copies are summed after the same fences; integer atomic adds commute -> deterministic.
__global__ __launch_bounds__(256) void select_kernel(u16* Sh, size_t sstride)
{
  __shared__ __align__(16) u32 hist[4][4][256];   // [wave][copy][bin] = 16 KB
  const int lane = threadIdx.x & 63;
  const int wave = threadIdx.x >> 6;
  const int cp   = lane & 3;
  const int row  = (blockIdx.x << 2) + wave;
  u16* Srow = Sh + (size_t)blockIdx.y * sstride + (size_t)row * NTOK + (lane << 3);

  u32 key[64];
  u32 umax = 0;
  #pragma unroll
  for (int g=0; g<8; ++g) {
    u32x4 q = *(const u32x4*)(Srow + (g<<9));   // stripe g: 512 elements
    #pragma unroll
    for (int j=0; j<4; ++j) {
      u32 w = q[j];
      u32 a = w & 0xFFFFu, bb = w >> 16;
      a  = (a  & 0x8000u) ? ((~a)  & 0xFFFFu) : (a  | 0x8000u);
      bb = (bb & 0x8000u) ? ((~bb) & 0xFFFFu) : (bb | 0x8000u);
      key[(g<<3)+(j<<1)  ] = a;
      key[(g<<3)+(j<<1)+1] = bb;
      umax = umax > a  ? umax : a;
      umax = umax > bb ? umax : bb;
    }
  }
  #pragma unroll
  for (int off=32; off; off>>=1) { u32 o = __shfl_xor(umax, off, 64); umax = o>umax ? o : umax; }
  const float m = kinv16(umax);

  u32 krem = KSEL, prefix = 0, cb = 0;
  #pragma unroll
  for (int pass=0; pass<2; ++pass) {
    #pragma unroll
    for (int c=0;c<4;c++)
      #pragma unroll
      for (int i=0;i<4;i++) hist[wave][c][(i<<6)+lane] = 0u;
    __asm__ volatile("s_waitcnt lgkmcnt(0)" ::: "memory");
    if (pass == 0) {
      #pragma unroll
      for (int ch=0; ch<64; ch++) atomicAdd(&hist[wave][cp][key[ch] >> 8], 1u);
    } else {
      const u32 b1 = prefix >> 8;
      #pragma unroll
      for (int ch=0; ch<64; ch++)
        if ((key[ch] >> 8) == b1) atomicAdd(&hist[wave][cp][key[ch] & 255u], 1u);
    }
    __asm__ volatile("s_waitcnt lgkmcnt(0)" ::: "memory");
    u32x4 h = *(const u32x4*)&hist[wave][0][lane<<2];
    #pragma unroll
    for (int c=1;c<4;c++) {
      u32x4 t = *(const u32x4*)&hist[wave][c][lane<<2];
      h[0]+=t[0]; h[1]+=t[1]; h[2]+=t[2]; h[3]+=t[3];
    }
    u32 tot = h[0]+h[1]+h[2]+h[3];
    u32 sfx = tot;
    #pragma unroll
    for (int off=1; off<64; off<<=1) {
      u32 v = __shfl_down(sfx, off, 64);
      if (lane + off < 64) sfx += v;
    }
    u32 s3 = (sfx - tot) + h[3];
    u32 s2 = s3 + h[2];
    u32 s1 = s2 + h[1];
    u32 s0 = s1 + h[0];
    u32 s4 = s3 - h[3];
    u32 kr = krem;
    u32 enc = 0;
    const int shift = 8 - (pass<<3);           // 8 then 0
    if (s0 >= kr && s1 < kr) enc = ((u32)((lane<<2)+0)<<22) | (h[0]<<9) | (kr - s1);
    if (s1 >= kr && s2 < kr) enc = ((u32)((lane<<2)+1)<<22) | (h[1]<<9) | (kr - s2);
    if (s2 >= kr && s3 < kr) enc = ((u32)((lane<<2)+2)<<22) | (h[2]<<9) | (kr - s3);
    if (s3 >= kr && s4 < kr) enc = ((u32)((lane<<2)+3)<<22) | (h[3]<<9) | (kr - s4);
    #pragma unroll
    for (int off=32; off; off>>=1) { u32 o = __shfl_xor(enc, off, 64); enc = (o>enc)? o:enc; }
    prefix |= (enc >> 22) << shift;
    cb      = (enc >> 9) & 0x1FFFu;
    krem    = enc & 0x1FFu;
  }
  const u32 tkey = prefix;                    // exact KSEL-th-largest fp16 key

  // selection bitmask
  u64 selb = 0;
  if (cb == krem) {
    #pragma unroll
    for (int ch=0; ch<64; ch++)
      if (key[ch] >= tkey) selb |= (1ull << ch);
  } else {
    const u64 ltmask = (1ull << lane) - 1ull;
    int eqbase = 0;
    #pragma unroll
    for (int ch=0; ch<64; ch++) {
      bool eq = (key[ch] == tkey);
      u64 eqm = __ballot(eq);
      bool sel = (key[ch] > tkey) || (eq && (eqbase + __popcll(eqm & ltmask)) < (int)krem);
      if (sel) selb |= (1ull << ch);
      eqbase += __popcll(eqm);
    }
  }

  // exp + denominator (cache e in key regs)
  float z = 0.f;
  #pragma unroll
  for (int ch=0; ch<64; ch++) {
    float e = __expf(kinv16(key[ch]) - m);
    if ((selb >> ch) & 1ull) z += e;
    key[ch] = __float_as_uint(e);
  }
  #pragma unroll
  for (int off=32; off; off>>=1) z += __shfl_xor(z, off, 64);
  const float invZ = 1.f / z;

  // coalesced in-place weight write (same addresses the row was read from)
  #pragma unroll
  for (int g=0; g<8; ++g) {
    u32x4 v;
    #pragma unroll
    for (int j=0; j<4; ++j) {
      int i0 = (g<<3)+(j<<1), i1 = i0+1;
      float w0 = ((selb >> i0) & 1ull) ? __uint_as_float(key[i0]) * invZ : 0.f;
      float w1 = ((selb >> i1) & 1ull) ? __uint_as_float(key[i1]) * invZ : 0.f;
      v[j] = (u32)h2u((_Float16)w0) | ((u32)h2u((_Float16)w1) << 16);
    }
    *(u32x4*)(Srow + (g<<9)) = v;
  }
}

// ---------------- phase 3: dense PV GEMM, 2-deep counted-vmcnt pipeline ----------------
// out^T[c,n] = sum_k Vc[c,k] * Wd[n,k].  128(M=ch) x 64(N=tok) tiles, K=NTOK, BK=64.
// Wd aliases S: freshly rewritten by select -> L3-resident at launch.
#define STAGE_PV(LA, LB, KT)                                                  \
  {                                                                           \
    _Pragma("unroll")                                                         \
    for (int c=0;c<4;c++) {                                                   \
      int r  = (c<<5) + sr;                                                   \
      int ss = sslot ^ (r & 7);                                               \
      gload16(Ag + (size_t)r*NTOK + ((KT)<<6) + (ss<<3),                      \
              (char*)(LA) + (c<<12) + (wave<<10));                            \
    }                                                                         \
    _Pragma("unroll")                                                         \
    for (int c=0;c<2;c++) {                                                   \
      int r  = (c<<5) + sr;                                                   \
      int ss = sslot ^ (r & 7);                                               \
      gload16(Bg + (size_t)r*NTOK + ((KT)<<6) + (ss<<3),                      \
              (char*)(LB) + (c<<12) + (wave<<10));                            \
    }                                                                         \
  }

#define COMP_PV(LA, LB)                                                       \
  {                                                                           \
    _Pragma("unroll")                                                         \
    for (int ks=0;ks<2;ks++) {                                                \
      half8 af[4], bf[2];                                                     \
      const int kg = lane >> 4;                                               \
      const int rl = lane & 15;                                               \
      const int slot = (ks<<2) + kg;                                          \
      _Pragma("unroll")                                                       \
      for (int t=0;t<4;t++) {                                                 \
        int ar = (wm<<6) + (t<<4) + rl;                                       \
        af[t] = *(const half8*)&(LA)[ar*64 + ((slot ^ (ar&7))<<3)];           \
      }                                                                       \
      _Pragma("unroll")                                                       \
      for (int t=0;t<2;t++) {                                                 \
        int br = (wn<<5) + (t<<4) + rl;                                       \
        bf[t] = *(const half8*)&(LB)[br*64 + ((slot ^ (br&7))<<3)];           \
      }                                                                       \
      _Pragma("unroll")                                                       \
      for (int mt=0;mt<4;mt++)                                                \
        _Pragma("unroll")                                                     \
        for (int nt=0;nt<2;nt++)                                              \
          acc[mt][nt] = __builtin_amdgcn_mfma_f32_16x16x32_f16(af[mt], bf[nt], acc[mt][nt], 0,0,0); \
    }                                                                         \
  }

#define PV_ITER(LA, LB, VM, TS)                                               \
  WAITV(VM); RBAR(); SCHED0();                                                \
  COMP_PV(LA, LB);                                                            \
  RBAR(); SCHED0();                                                           \
  if ((TS) < 64) STAGE_PV(LA, LB, TS);

__global__ __launch_bounds__(256) void pv_gemm(
    const u16* __restrict__ Vc, const u16* __restrict__ Wd,
    float* __restrict__ out, int b_base, size_t wstride)
{
  __shared__ __align__(16) short lds_a0[128*64];   // 16 KB x2
  __shared__ __align__(16) short lds_a1[128*64];
  __shared__ __align__(16) short lds_b0[64*64];    //  8 KB x2
  __shared__ __align__(16) short lds_b1[64*64];
  const int tid  = threadIdx.x;
  const int lane = tid & 63;
  const int wave = tid >> 6;
  const int wm = wave >> 1, wn = wave & 1;
  const int b    = b_base + blockIdx.z;
  const int brow = blockIdx.x << 7;      // channel tile (0/128)
  const int bcol = blockIdx.y << 6;      // token tile (64-wide)

  const u16* Ag = Vc + (size_t)b*CH*NTOK + (size_t)brow*NTOK;
  const u16* Bg = Wd + (size_t)blockIdx.z*wstride + (size_t)bcol*NTOK;

  f32x4 acc[4][2];
  #pragma unroll
  for (int i=0;i<4;i++)
    #pragma unroll
    for (int j=0;j<2;j++) acc[i][j] = (f32x4)0.f;

  const int sr    = tid >> 3;
  const int sslot = tid & 7;

  STAGE_PV(lds_a0, lds_b0, 0);
  STAGE_PV(lds_a1, lds_b1, 1);

  for (int g=0; g<31; ++g) {               // t = 0..61
    const int t = g*2;
    PV_ITER(lds_a0, lds_b0, "vmcnt(6)", t+2);
    PV_ITER(lds_a1, lds_b1, "vmcnt(6)", t+3);
  }
  // tail: t=62, t=63
  WAITV("vmcnt(6)"); RBAR(); SCHED0();
  COMP_PV(lds_a0, lds_b0);
  RBAR(); SCHED0();
  WAITV("vmcnt(0)"); RBAR(); SCHED0();
  COMP_PV(lds_a1, lds_b1);

  float* ob = out + (size_t)b*CH*NTOK;
  const int rl = lane & 15, rg = lane >> 4;
  #pragma unroll
  for (int mt=0;mt<4;mt++) {
    #pragma unroll
    for (int nt=0;nt<2;nt++) {
      int row = brow + (wm<<6) + (mt<<4) + (rg<<2);   // channel
      int col = bcol + (wn<<5) + (nt<<4) + rl;        // token
      #pragma unroll
      for (int r=0;r<4;r++)
        ob[(size_t)(row+r)*NTOK + col] = acc[mt][nt][r];
    }
  }
}

// ---------------- launcher ----------------
extern "C" void kernel_launch(void* const* d_in, const int* in_sizes, int n_in,
                              void* d_out, int out_size, void* d_ws, size_t ws_size,
                              hipStream_t stream)
{
  (void)in_sizes; (void)n_in; (void)out_size;
  const float* x  = (const float*)d_in[0];
  const float* Wq = (const float*)d_in[1];
  const float* Wk = (const float*)d_in[2];
  const float* Wv = (const float*)d_in[3];
  float* out = (float*)d_out;

  char* ws = (char*)d_ws;
  size_t off = 0;
  const size_t plane = (size_t)BATCH*NTOK*CH*2;       // 8.4 MB fp16 plane
  const size_t NN    = (size_t)NTOK*NTOK;             // 16.8M elements
  u16* Qh = (u16*)(ws + off); off += plane;
  u16* Kh = (u16*)(ws + off); off += plane;
  u16* Vc = (u16*)(ws + off); off += plane;
  u16* W3h = (u16*)(ws + off); off += (size_t)3*CH*CH*2;
  u16* W3l = (u16*)(ws + off); off += (size_t)3*CH*CH*2;
  // xT planes live only until proj_gemm completes; S (== W, in-place) overlaps them after.
  const size_t xt_base = off;
  u16* xTh = (u16*)(ws + xt_base);
  u16* xTl = (u16*)(ws + xt_base + plane);
  u16* S   = (u16*)(ws + xt_base);
  const size_t full_need = xt_base + (size_t)BATCH*NN*2;   // ~160 MiB: S[4] fp16, W aliases S
  const bool full = ws_size >= full_need;

  wsplit_kernel<<<dim3(64,3), 256, 0, stream>>>(Wq, Wk, Wv, W3h, W3l);
  xsplit_kernel<<<dim3(64,4,4), 256, 0, stream>>>(x, xTh, xTl);
  proj_gemm<<<dim3(32,2,12), 256, 0, stream>>>(xTh, xTl, W3h, W3l, Qh, Kh, Vc);

  if (full) {
    // all scores -> all selects (in-place S->W) -> pv ; last-touched 134MB = W -> L3-hot for pv
    score_kernel<<<dim3(32,32,4), 256, 0, stream>>>(Qh, Kh, S, 0, NN);
    select_kernel<<<dim3(1024,4), 256, 0, stream>>>(S, NN);
    pv_gemm<<<dim3(2,64,4), 256, 0, stream>>>(Vc, S, out, 0, NN);
  } else {
    // low-ws fallback: per-batch, single S buffer (33.5 MB), still in-place
    for (int b=0; b<BATCH; b++) {
      score_kernel<<<dim3(32,32,1), 256, 0, stream>>>(Qh, Kh, S, b, 0);
      select_kernel<<<dim3(1024,1), 256, 0, stream>>>(S, 0);
      pv_gemm<<<dim3(2,64,1), 256, 0, stream>>>(Vc, S, out, b, 0);
    }
  }
}

// Round 21
// 228.158 us; speedup vs baseline: 1.2203x; 1.0000x over previous
//
#include <hip/hip_runtime.h>
#include <stdint.h>

#define BATCH 4
#define CH    256
#define NTOK  4096
#define KSEL  409          // int(0.1 * 4096)

typedef unsigned short u16;
typedef unsigned int   u32;
typedef unsigned long long u64;

typedef __attribute__((ext_vector_type(8))) _Float16 half8;
typedef __attribute__((ext_vector_type(4))) _Float16 half4;
typedef __attribute__((ext_vector_type(4))) float f32x4;
typedef __attribute__((ext_vector_type(4))) u32 u32x4;
typedef __attribute__((ext_vector_type(2))) u32 u32x2;
typedef __attribute__((ext_vector_type(4))) float fl4;

// ---------------- helpers ----------------
__device__ inline u16 h2u(_Float16 h){ u16 u; __builtin_memcpy(&u,&h,2); return u; }
__device__ inline float u2f16(u32 v){ _Float16 h; u16 uu=(u16)v; __builtin_memcpy(&h,&uu,2); return (float)h; }
// monotone 16-bit fp16<->uint key transform (ascending)
__device__ inline float kinv16(u32 k){
  u32 v = (k & 0x8000u) ? (k & 0x7FFFu) : ((~k) & 0xFFFFu);
  return u2f16(v);
}
__device__ inline void gload16(const void* g, void* l){
  __builtin_amdgcn_global_load_lds((const __attribute__((address_space(1))) u32*)g,
                                   (__attribute__((address_space(3))) u32*)l, 16, 0, 0);
}

// ---------------- phase -1: W split ----------------
__global__ __launch_bounds__(256) void wsplit_kernel(
    const float* __restrict__ Wq, const float* __restrict__ Wk,
    const float* __restrict__ Wv, u16* __restrict__ W3h, u16* __restrict__ W3l)
{
  const int p = blockIdx.y;
  const float* W = (p==0)? Wq : (p==1)? Wk : Wv;
  const int idx = (blockIdx.x*256 + threadIdx.x) * 4;
  fl4 v = *(const fl4*)(W + idx);
  u32x2 vh, vl;
  #pragma unroll
  for (int q=0;q<2;q++) {
    _Float16 h0=(_Float16)v[q*2], h1=(_Float16)v[q*2+1];
    _Float16 l0=(_Float16)(v[q*2]-(float)h0), l1=(_Float16)(v[q*2+1]-(float)h1);
    vh[q] = (u32)h2u(h0) | ((u32)h2u(h1)<<16);
    vl[q] = (u32)h2u(l0) | ((u32)h2u(l1)<<16);
  }
  *(u32x2*)(W3h + p*CH*CH + idx) = vh;
  *(u32x2*)(W3l + p*CH*CH + idx) = vl;
}

// ---------------- phase 0a: x transpose + split ----------------
__global__ __launch_bounds__(256) void xsplit_kernel(
    const float* __restrict__ x, u16* __restrict__ xTh, u16* __restrict__ xTl)
{
  __shared__ float lds[64][65];
  const int tid = threadIdx.x;
  const int n0 = blockIdx.x << 6;
  const int c0 = blockIdx.y << 6;
  const int b  = blockIdx.z;
  const float* xb = x + (size_t)b*CH*NTOK;

  #pragma unroll
  for (int i=0;i<16;i++) {
    int c_l = (tid>>6) + (i<<2);
    int n_l = tid & 63;
    lds[c_l][n_l] = xb[(size_t)(c0+c_l)*NTOK + n0 + n_l];
  }
  __syncthreads();
  u16* oh = xTh + (size_t)b*NTOK*CH;
  u16* ol = xTl + (size_t)b*NTOK*CH;
  #pragma unroll
  for (int i=0;i<16;i++) {
    int n_l = (tid>>6) + (i<<2);
    int c_l = tid & 63;
    float v = lds[c_l][n_l];
    _Float16 h = (_Float16)v;
    _Float16 l = (_Float16)(v - (float)h);
    size_t o = (size_t)(n0+n_l)*CH + c0 + c_l;
    oh[o] = h2u(h);
    ol[o] = h2u(l);
  }
}

// ---------------- phase 0b: QKV projection GEMM ----------------
__global__ __launch_bounds__(256) void proj_gemm(
    const u16* __restrict__ xTh, const u16* __restrict__ xTl,
    const u16* __restrict__ W3h, const u16* __restrict__ W3l,
    u16* __restrict__ Qh, u16* __restrict__ Kh, u16* __restrict__ Vc)
{
  __shared__ __align__(16) short lds[4*128*64];   // ah, al, bh, bl (16KB each)
  short* lds_ah = lds;
  short* lds_al = lds + 128*64;
  short* lds_bh = lds + 2*128*64;
  short* lds_bl = lds + 3*128*64;

  const int tid  = threadIdx.x;
  const int lane = tid & 63;
  const int wave = tid >> 6;
  const int wm = wave >> 1, wn = wave & 1;
  const int brow = blockIdx.x << 7;     // token tile
  const int bcol = blockIdx.y << 7;     // out-channel tile
  const int z = blockIdx.z;             // b*3 + p
  const int b = z / 3, p = z - 3*b;

  const u16* Agh = xTh + ((size_t)b*NTOK + brow)*CH;
  const u16* Agl = xTl + ((size_t)b*NTOK + brow)*CH;
  const u16* Bgh = W3h + (size_t)p*CH*CH + (size_t)bcol*CH;
  const u16* Bgl = W3l + (size_t)p*CH*CH + (size_t)bcol*CH;

  f32x4 acc[4][4];
  #pragma unroll
  for (int i=0;i<4;i++)
    #pragma unroll
    for (int j=0;j<4;j++) acc[i][j] = (f32x4)0.f;

  const int sr    = tid >> 3;
  const int sslot = tid & 7;

  for (int kt=0; kt<4; kt++) {
    #pragma unroll
    for (int c=0;c<4;c++) {
      int r  = (c<<5) + sr;
      int ss = sslot ^ (r & 7);
      size_t goff = (size_t)r*CH + (kt<<6) + (ss<<3);
      int dst = (c<<12) + (wave<<10);
      gload16(Agh + goff, (char*)lds_ah + dst);
      gload16(Agl + goff, (char*)lds_al + dst);
      gload16(Bgh + goff, (char*)lds_bh + dst);
      gload16(Bgl + goff, (char*)lds_bl + dst);
    }
    __syncthreads();
    #pragma unroll
    for (int ks=0;ks<2;ks++) {
      half8 ah[4], al[4], bh[4], bl[4];
      const int kg = lane >> 4;
      const int rl = lane & 15;
      #pragma unroll
      for (int t=0;t<4;t++) {
        int ar = (wm<<6) + (t<<4) + rl;
        int slot = (ks<<2) + kg;
        int ao = ar*64 + ((slot ^ (ar&7))<<3);
        ah[t] = *(const half8*)&lds_ah[ao];
        al[t] = *(const half8*)&lds_al[ao];
        int br = (wn<<6) + (t<<4) + rl;
        int bo = br*64 + ((slot ^ (br&7))<<3);
        bh[t] = *(const half8*)&lds_bh[bo];
        bl[t] = *(const half8*)&lds_bl[bo];
      }
      #pragma unroll
      for (int mt=0;mt<4;mt++)
        #pragma unroll
        for (int nt=0;nt<4;nt++) {
          acc[mt][nt] = __builtin_amdgcn_mfma_f32_16x16x32_f16(ah[mt], bh[nt], acc[mt][nt], 0,0,0);
          acc[mt][nt] = __builtin_amdgcn_mfma_f32_16x16x32_f16(ah[mt], bl[nt], acc[mt][nt], 0,0,0);
          acc[mt][nt] = __builtin_amdgcn_mfma_f32_16x16x32_f16(al[mt], bh[nt], acc[mt][nt], 0,0,0);
        }
    }
    __syncthreads();
  }

  const int rl = lane & 15, rg = lane >> 4;
  if (p < 2) {
    u16* oh = ((p==0)? Qh : Kh) + (size_t)b*NTOK*CH;
    #pragma unroll
    for (int mt=0;mt<4;mt++) {
      #pragma unroll
      for (int nt=0;nt<4;nt++) {
        int n = brow + (wm<<6) + (mt<<4) + (rg<<2);
        int c = bcol + (wn<<6) + (nt<<4) + rl;
        #pragma unroll
        for (int r=0;r<4;r++)
          oh[(size_t)(n+r)*CH + c] = h2u((_Float16)acc[mt][nt][r]);
      }
    }
  } else {
    // V: transpose in LDS -> store channel-major Vc[b][d][n] coalesced
    u16* ldsT = (u16*)lds;                 // [128][136] u16
    #pragma unroll
    for (int mt=0;mt<4;mt++) {
      #pragma unroll
      for (int nt=0;nt<4;nt++) {
        int n_l = (wm<<6) + (mt<<4) + (rg<<2);
        int c_l = (wn<<6) + (nt<<4) + rl;
        half4 hv;
        #pragma unroll
        for (int r=0;r<4;r++) hv[r] = (_Float16)acc[mt][nt][r];
        *(half4*)&ldsT[c_l*136 + n_l] = hv;
      }
    }
    __syncthreads();
    u16* ov = Vc + (size_t)b*CH*NTOK + (size_t)bcol*NTOK + brow;
    #pragma unroll
    for (int i=0;i<32;i++) {
      int d_l = (tid>>6) + (i<<2);
      u32 v = *(const u32*)&ldsT[d_l*136 + (lane<<1)];
      *(u32*)(ov + (size_t)d_l*NTOK + (lane<<1)) = v;
    }
  }
}

// ============ counted-vmcnt pipeline macros (T4: never drain vmcnt to 0 mid-loop) ============
#define WAITV(S)  asm volatile("s_waitcnt " S ::: "memory")
#define RBAR()    __builtin_amdgcn_s_barrier()
#define SCHED0()  __builtin_amdgcn_sched_barrier(0)

// ---------------- phase 1: S = Q*K^T / 16, hi-only fp16, fp16 out, 2-deep pipeline ----------------
#define STAGE_SC(LA, LB, KT)                                                  \
  {                                                                           \
    _Pragma("unroll")                                                         \
    for (int c=0;c<4;c++) {                                                   \
      int r  = (c<<5) + sr;                                                   \
      int ss = sslot ^ (r & 7);                                               \
      size_t goff = (size_t)r*CH + ((KT)<<6) + (ss<<3);                       \
      gload16(Ag + goff, (char*)(LA) + (c<<12) + (wave<<10));                 \
      gload16(Bg + goff, (char*)(LB) + (c<<12) + (wave<<10));                 \
    }                                                                         \
  }

#define COMP_SC(LA, LB)                                                       \
  {                                                                           \
    _Pragma("unroll")                                                         \
    for (int ks=0;ks<2;ks++) {                                                \
      half8 af[4], bf[4];                                                     \
      const int kg = lane >> 4;                                               \
      const int rl = lane & 15;                                               \
      _Pragma("unroll")                                                       \
      for (int t=0;t<4;t++) {                                                 \
        int ar = (wm<<6) + (t<<4) + rl;                                       \
        int slot = (ks<<2) + kg;                                              \
        af[t] = *(const half8*)&(LA)[ar*64 + ((slot ^ (ar&7))<<3)];           \
        int br = (wn<<6) + (t<<4) + rl;                                       \
        bf[t] = *(const half8*)&(LB)[br*64 + ((slot ^ (br&7))<<3)];           \
      }                                                                       \
      _Pragma("unroll")                                                       \
      for (int mt=0;mt<4;mt++)                                                \
        _Pragma("unroll")                                                     \
        for (int nt=0;nt<4;nt++)                                              \
          acc[mt][nt] = __builtin_amdgcn_mfma_f32_16x16x32_f16(af[mt], bf[nt], acc[mt][nt], 0,0,0); \
    }                                                                         \
  }

__global__ __launch_bounds__(256) void score_kernel(
    const u16* __restrict__ Qh, const u16* __restrict__ Kh,
    u16* __restrict__ S, int b_base, size_t sstride)
{
  __shared__ __align__(16) short lds_a0[128*64];
  __shared__ __align__(16) short lds_a1[128*64];
  __shared__ __align__(16) short lds_b0[128*64];
  __shared__ __align__(16) short lds_b1[128*64];
  const int tid  = threadIdx.x;
  const int lane = tid & 63;
  const int wave = tid >> 6;
  const int wm = wave >> 1, wn = wave & 1;
  const int brow = blockIdx.x << 7, bcol = blockIdx.y << 7;
  const int b = b_base + blockIdx.z;
  u16* Sb = S + (size_t)blockIdx.z * sstride;

  const u16* Ag = Qh + ((size_t)b*NTOK + brow)*CH;
  const u16* Bg = Kh + ((size_t)b*NTOK + bcol)*CH;

  f32x4 acc[4][4];
  #pragma unroll
  for (int i=0;i<4;i++)
    #pragma unroll
    for (int j=0;j<4;j++) acc[i][j] = (f32x4)0.f;

  const int sr    = tid >> 3;
  const int sslot = tid & 7;

  STAGE_SC(lds_a0, lds_b0, 0);
  STAGE_SC(lds_a1, lds_b1, 1);
  // t=0
  WAITV("vmcnt(8)"); RBAR(); SCHED0();
  COMP_SC(lds_a0, lds_b0);
  RBAR(); SCHED0();
  STAGE_SC(lds_a0, lds_b0, 2);
  // t=1
  WAITV("vmcnt(8)"); RBAR(); SCHED0();
  COMP_SC(lds_a1, lds_b1);
  RBAR(); SCHED0();
  STAGE_SC(lds_a1, lds_b1, 3);
  // t=2
  WAITV("vmcnt(8)"); RBAR(); SCHED0();
  COMP_SC(lds_a0, lds_b0);
  RBAR(); SCHED0();
  // t=3
  WAITV("vmcnt(0)"); RBAR(); SCHED0();
  COMP_SC(lds_a1, lds_b1);

  const int rl = lane & 15, rg = lane >> 4;
  #pragma unroll
  for (int mt=0;mt<4;mt++) {
    #pragma unroll
    for (int nt=0;nt<4;nt++) {
      int row = brow + (wm<<6) + (mt<<4) + (rg<<2);
      int col = bcol + (wn<<6) + (nt<<4) + rl;
      #pragma unroll
      for (int r=0;r<4;r++)
        Sb[(size_t)(row+r)*NTOK + col] = h2u((_Float16)(acc[mt][nt][r] * 0.0625f));
    }
  }
}

// ---------------- phase 2: exact per-row top-KSEL on fp16 scores, IN-PLACE S->W ----------------
// Round-14 semantics (canary absmax 1.123047e-2) with ONE change vs round 20:
// BANK-INTERLEAVED 4-copy sub-histograms: word index = bin*4 + (lane&3), so the 4 copies
// of one bin live in 4 DIFFERENT banks (round-20's [cp][bin] layout put all copies of a
// bin in the SAME bank -> zero effect, conflict counter unchanged at 5.9M).
// Copies summed after the same fences; integer atomic adds commute -> deterministic.
__global__ __launch_bounds__(256) void select_kernel(u16* Sh, size_t sstride)
{
  __shared__ __align__(16) u32 hist[4][1024];   // [wave][bin*4+copy] = 16 KB
  const int lane = threadIdx.x & 63;
  const int wave = threadIdx.x >> 6;
  const int cp   = lane & 3;
  const int row  = (blockIdx.x << 2) + wave;
  u16* Srow = Sh + (size_t)blockIdx.y * sstride + (size_t)row * NTOK + (lane << 3);

  u32 key[64];
  u32 umax = 0;
  #pragma unroll
  for (int g=0; g<8; ++g) {
    u32x4 q = *(const u32x4*)(Srow + (g<<9));   // stripe g: 512 elements
    #pragma unroll
    for (int j=0; j<4; ++j) {
      u32 w = q[j];
      u32 a = w & 0xFFFFu, bb = w >> 16;
      a  = (a  & 0x8000u) ? ((~a)  & 0xFFFFu) : (a  | 0x8000u);
      bb = (bb & 0x8000u) ? ((~bb) & 0xFFFFu) : (bb | 0x8000u);
      key[(g<<3)+(j<<1)  ] = a;
      key[(g<<3)+(j<<1)+1] = bb;
      umax = umax > a  ? umax : a;
      umax = umax > bb ? umax : bb;
    }
  }
  #pragma unroll
  for (int off=32; off; off>>=1) { u32 o = __shfl_xor(umax, off, 64); umax = o>umax ? o : umax; }
  const float m = kinv16(umax);

  u32 krem = KSEL, prefix = 0, cb = 0;
  #pragma unroll
  for (int pass=0; pass<2; ++pass) {
    #pragma unroll
    for (int i=0;i<16;i++) hist[wave][(i<<6)+lane] = 0u;
    __asm__ volatile("s_waitcnt lgkmcnt(0)" ::: "memory");
    if (pass == 0) {
      #pragma unroll
      for (int ch=0; ch<64; ch++) atomicAdd(&hist[wave][((key[ch] >> 8)<<2) + cp], 1u);
    } else {
      const u32 b1 = prefix >> 8;
      #pragma unroll
      for (int ch=0; ch<64; ch++)
        if ((key[ch] >> 8) == b1) atomicAdd(&hist[wave][((key[ch] & 255u)<<2) + cp], 1u);
    }
    __asm__ volatile("s_waitcnt lgkmcnt(0)" ::: "memory");
    // bins 4*lane .. 4*lane+3 -> words [lane*16 .. lane*16+15], copy-sum each bin
    u32x4 v0 = *(const u32x4*)&hist[wave][(lane<<4)+ 0];
    u32x4 v1 = *(const u32x4*)&hist[wave][(lane<<4)+ 4];
    u32x4 v2 = *(const u32x4*)&hist[wave][(lane<<4)+ 8];
    u32x4 v3 = *(const u32x4*)&hist[wave][(lane<<4)+12];
    u32x4 h;
    h[0] = v0[0]+v0[1]+v0[2]+v0[3];
    h[1] = v1[0]+v1[1]+v1[2]+v1[3];
    h[2] = v2[0]+v2[1]+v2[2]+v2[3];
    h[3] = v3[0]+v3[1]+v3[2]+v3[3];
    u32 tot = h[0]+h[1]+h[2]+h[3];
    u32 sfx = tot;
    #pragma unroll
    for (int off=1; off<64; off<<=1) {
      u32 v = __shfl_down(sfx, off, 64);
      if (lane + off < 64) sfx += v;
    }
    u32 s3 = (sfx - tot) + h[3];
    u32 s2 = s3 + h[2];
    u32 s1 = s2 + h[1];
    u32 s0 = s1 + h[0];
    u32 s4 = s3 - h[3];
    u32 kr = krem;
    u32 enc = 0;
    const int shift = 8 - (pass<<3);           // 8 then 0
    if (s0 >= kr && s1 < kr) enc = ((u32)((lane<<2)+0)<<22) | (h[0]<<9) | (kr - s1);
    if (s1 >= kr && s2 < kr) enc = ((u32)((lane<<2)+1)<<22) | (h[1]<<9) | (kr - s2);
    if (s2 >= kr && s3 < kr) enc = ((u32)((lane<<2)+2)<<22) | (h[2]<<9) | (kr - s3);
    if (s3 >= kr && s4 < kr) enc = ((u32)((lane<<2)+3)<<22) | (h[3]<<9) | (kr - s4);
    #pragma unroll
    for (int off=32; off; off>>=1) { u32 o = __shfl_xor(enc, off, 64); enc = (o>enc)? o:enc; }
    prefix |= (enc >> 22) << shift;
    cb      = (enc >> 9) & 0x1FFFu;
    krem    = enc & 0x1FFu;
  }
  const u32 tkey = prefix;                    // exact KSEL-th-largest fp16 key

  // selection bitmask
  u64 selb = 0;
  if (cb == krem) {
    #pragma unroll
    for (int ch=0; ch<64; ch++)
      if (key[ch] >= tkey) selb |= (1ull << ch);
  } else {
    const u64 ltmask = (1ull << lane) - 1ull;
    int eqbase = 0;
    #pragma unroll
    for (int ch=0; ch<64; ch++) {
      bool eq = (key[ch] == tkey);
      u64 eqm = __ballot(eq);
      bool sel = (key[ch] > tkey) || (eq && (eqbase + __popcll(eqm & ltmask)) < (int)krem);
      if (sel) selb |= (1ull << ch);
      eqbase += __popcll(eqm);
    }
  }

  // exp + denominator (cache e in key regs)
  float z = 0.f;
  #pragma unroll
  for (int ch=0; ch<64; ch++) {
    float e = __expf(kinv16(key[ch]) - m);
    if ((selb >> ch) & 1ull) z += e;
    key[ch] = __float_as_uint(e);
  }
  #pragma unroll
  for (int off=32; off; off>>=1) z += __shfl_xor(z, off, 64);
  const float invZ = 1.f / z;

  // coalesced in-place weight write (same addresses the row was read from)
  #pragma unroll
  for (int g=0; g<8; ++g) {
    u32x4 v;
    #pragma unroll
    for (int j=0; j<4; ++j) {
      int i0 = (g<<3)+(j<<1), i1 = i0+1;
      float w0 = ((selb >> i0) & 1ull) ? __uint_as_float(key[i0]) * invZ : 0.f;
      float w1 = ((selb >> i1) & 1ull) ? __uint_as_float(key[i1]) * invZ : 0.f;
      v[j] = (u32)h2u((_Float16)w0) | ((u32)h2u((_Float16)w1) << 16);
    }
    *(u32x4*)(Srow + (g<<9)) = v;
  }
}

// ---------------- phase 3: dense PV GEMM, 2-deep counted-vmcnt pipeline ----------------
// out^T[c,n] = sum_k Vc[c,k] * Wd[n,k].  128(M=ch) x 64(N=tok) tiles, K=NTOK, BK=64.
// Wd aliases S: freshly rewritten by select -> L3-resident at launch.
#define STAGE_PV(LA, LB, KT)                                                  \
  {                                                                           \
    _Pragma("unroll")                                                         \
    for (int c=0;c<4;c++) {                                                   \
      int r  = (c<<5) + sr;                                                   \
      int ss = sslot ^ (r & 7);                                               \
      gload16(Ag + (size_t)r*NTOK + ((KT)<<6) + (ss<<3),                      \
              (char*)(LA) + (c<<12) + (wave<<10));                            \
    }                                                                         \
    _Pragma("unroll")                                                         \
    for (int c=0;c<2;c++) {                                                   \
      int r  = (c<<5) + sr;                                                   \
      int ss = sslot ^ (r & 7);                                               \
      gload16(Bg + (size_t)r*NTOK + ((KT)<<6) + (ss<<3),                      \
              (char*)(LB) + (c<<12) + (wave<<10));                            \
    }                                                                         \
  }

#define COMP_PV(LA, LB)                                                       \
  {                                                                           \
    _Pragma("unroll")                                                         \
    for (int ks=0;ks<2;ks++) {                                                \
      half8 af[4], bf[2];                                                     \
      const int kg = lane >> 4;                                               \
      const int rl = lane & 15;                                               \
      const int slot = (ks<<2) + kg;                                          \
      _Pragma("unroll")                                                       \
      for (int t=0;t<4;t++) {                                                 \
        int ar = (wm<<6) + (t<<4) + rl;                                       \
        af[t] = *(const half8*)&(LA)[ar*64 + ((slot ^ (ar&7))<<3)];           \
      }                                                                       \
      _Pragma("unroll")                                                       \
      for (int t=0;t<2;t++) {                                                 \
        int br = (wn<<5) + (t<<4) + rl;                                       \
        bf[t] = *(const half8*)&(LB)[br*64 + ((slot ^ (br&7))<<3)];           \
      }                                                                       \
      _Pragma("unroll")                                                       \
      for (int mt=0;mt<4;mt++)                                                \
        _Pragma("unroll")                                                     \
        for (int nt=0;nt<2;nt++)                                              \
          acc[mt][nt] = __builtin_amdgcn_mfma_f32_16x16x32_f16(af[mt], bf[nt], acc[mt][nt], 0,0,0); \
    }                                                                         \
  }

#define PV_ITER(LA, LB, VM, TS)                                               \
  WAITV(VM); RBAR(); SCHED0();                                                \
  COMP_PV(LA, LB);                                                            \
  RBAR(); SCHED0();                                                           \
  if ((TS) < 64) STAGE_PV(LA, LB, TS);

__global__ __launch_bounds__(256) void pv_gemm(
    const u16* __restrict__ Vc, const u16* __restrict__ Wd,
    float* __restrict__ out, int b_base, size_t wstride)
{
  __shared__ __align__(16) short lds_a0[128*64];   // 16 KB x2
  __shared__ __align__(16) short lds_a1[128*64];
  __shared__ __align__(16) short lds_b0[64*64];    //  8 KB x2
  __shared__ __align__(16) short lds_b1[64*64];
  const int tid  = threadIdx.x;
  const int lane = tid & 63;
  const int wave = tid >> 6;
  const int wm = wave >> 1, wn = wave & 1;
  const int b    = b_base + blockIdx.z;
  const int brow = blockIdx.x << 7;      // channel tile (0/128)
  const int bcol = blockIdx.y << 6;      // token tile (64-wide)

  const u16* Ag = Vc + (size_t)b*CH*NTOK + (size_t)brow*NTOK;
  const u16* Bg = Wd + (size_t)blockIdx.z*wstride + (size_t)bcol*NTOK;

  f32x4 acc[4][2];
  #pragma unroll
  for (int i=0;i<4;i++)
    #pragma unroll
    for (int j=0;j<2;j++) acc[i][j] = (f32x4)0.f;

  const int sr    = tid >> 3;
  const int sslot = tid & 7;

  STAGE_PV(lds_a0, lds_b0, 0);
  STAGE_PV(lds_a1, lds_b1, 1);

  for (int g=0; g<31; ++g) {               // t = 0..61
    const int t = g*2;
    PV_ITER(lds_a0, lds_b0, "vmcnt(6)", t+2);
    PV_ITER(lds_a1, lds_b1, "vmcnt(6)", t+3);
  }
  // tail: t=62, t=63
  WAITV("vmcnt(6)"); RBAR(); SCHED0();
  COMP_PV(lds_a0, lds_b0);
  RBAR(); SCHED0();
  WAITV("vmcnt(0)"); RBAR(); SCHED0();
  COMP_PV(lds_a1, lds_b1);

  float* ob = out + (size_t)b*CH*NTOK;
  const int rl = lane & 15, rg = lane >> 4;
  #pragma unroll
  for (int mt=0;mt<4;mt++) {
    #pragma unroll
    for (int nt=0;nt<2;nt++) {
      int row = brow + (wm<<6) + (mt<<4) + (rg<<2);   // channel
      int col = bcol + (wn<<5) + (nt<<4) + rl;        // token
      #pragma unroll
      for (int r=0;r<4;r++)
        ob[(size_t)(row+r)*NTOK + col] = acc[mt][nt][r];
    }
  }
}

// ---------------- launcher ----------------
extern "C" void kernel_launch(void* const* d_in, const int* in_sizes, int n_in,
                              void* d_out, int out_size, void* d_ws, size_t ws_size,
                              hipStream_t stream)
{
  (void)in_sizes; (void)n_in; (void)out_size;
  const float* x  = (const float*)d_in[0];
  const float* Wq = (const float*)d_in[1];
  const float* Wk = (const float*)d_in[2];
  const float* Wv = (const float*)d_in[3];
  float* out = (float*)d_out;

  char* ws = (char*)d_ws;
  size_t off = 0;
  const size_t plane = (size_t)BATCH*NTOK*CH*2;       // 8.4 MB fp16 plane
  const size_t NN    = (size_t)NTOK*NTOK;             // 16.8M elements
  u16* Qh = (u16*)(ws + off); off += plane;
  u16* Kh = (u16*)(ws + off); off += plane;
  u16* Vc = (u16*)(ws + off); off += plane;
  u16* W3h = (u16*)(ws + off); off += (size_t)3*CH*CH*2;
  u16* W3l = (u16*)(ws + off); off += (size_t)3*CH*CH*2;
  // xT planes live only until proj_gemm completes; S (== W, in-place) overlaps them after.
  const size_t xt_base = off;
  u16* xTh = (u16*)(ws + xt_base);
  u16* xTl = (u16*)(ws + xt_base + plane);
  u16* S   = (u16*)(ws + xt_base);
  const size_t full_need = xt_base + (size_t)BATCH*NN*2;   // ~160 MiB: S[4] fp16, W aliases S
  const bool full = ws_size >= full_need;

  wsplit_kernel<<<dim3(64,3), 256, 0, stream>>>(Wq, Wk, Wv, W3h, W3l);
  xsplit_kernel<<<dim3(64,4,4), 256, 0, stream>>>(x, xTh, xTl);
  proj_gemm<<<dim3(32,2,12), 256, 0, stream>>>(xTh, xTl, W3h, W3l, Qh, Kh, Vc);

  if (full) {
    // all scores -> all selects (in-place S->W) -> pv ; last-touched 134MB = W -> L3-hot for pv
    score_kernel<<<dim3(32,32,4), 256, 0, stream>>>(Qh, Kh, S, 0, NN);
    select_kernel<<<dim3(1024,4), 256, 0, stream>>>(S, NN);
    pv_gemm<<<dim3(2,64,4), 256, 0, stream>>>(Vc, S, out, 0, NN);
  } else {
    // low-ws fallback: per-batch, single S buffer (33.5 MB), still in-place
    for (int b=0; b<BATCH; b++) {
      score_kernel<<<dim3(32,32,1), 256, 0, stream>>>(Qh, Kh, S, b, 0);
      select_kernel<<<dim3(1024,1), 256, 0, stream>>>(S, 0);
      pv_gemm<<<dim3(2,64,1), 256, 0, stream>>>(Vc, S, out, b, 0);
    }
  }
}